// Round 6
// baseline (3611.901 us; speedup 1.0000x reference)
//
#include <hip/hip_runtime.h>
#include <math.h>

#define NN 50000
#define E0 800000
#define ET 850000
#define NB 196  // ceil(NN/256) scan blocks
#define XS 68   // XsT row stride: 4*68 mod 32 = 16 -> 4-way store conflicts (was 8-way at 72)

typedef unsigned int uint32;
typedef unsigned short ushort16;

__device__ __forceinline__ ushort16 f2bf(float f) {
  uint32 u = __float_as_uint(f);
  return (ushort16)((u + 0x7FFFu + ((u >> 16) & 1u)) >> 16);  // RNE
}

// ---------------- CSR build ----------------

__global__ void zero_int_kernel(int* __restrict__ p, int n) {
  int i = blockIdx.x * blockDim.x + threadIdx.x;
  if (i < n) p[i] = 0;
}

__global__ void count_kernel(const int* __restrict__ ei, int* __restrict__ cnt) {
  int e = blockIdx.x * blockDim.x + threadIdx.x;
  if (e >= ET) return;
  int dst = (e < E0) ? ei[E0 + e] : (e - E0);
  atomicAdd(&cnt[dst], 1);
}

__global__ __launch_bounds__(256) void scan_l1_kernel(const int* __restrict__ cnt,
                                                      int* __restrict__ rowptr,
                                                      int* __restrict__ bsum) {
  __shared__ int s[256];
  int i = blockIdx.x * 256 + threadIdx.x;
  int v = (i < NN) ? cnt[i] : 0;
  int val = v;
  s[threadIdx.x] = val;
  __syncthreads();
#pragma unroll
  for (int off = 1; off < 256; off <<= 1) {
    int t = (threadIdx.x >= (unsigned)off) ? s[threadIdx.x - off] : 0;
    __syncthreads();
    val += t;
    s[threadIdx.x] = val;
    __syncthreads();
  }
  if (i < NN) rowptr[i] = val - v;  // block-local exclusive
  if (threadIdx.x == 255) bsum[blockIdx.x] = val;
}

__global__ __launch_bounds__(256) void scan_l2_kernel(const int* __restrict__ bsum,
                                                      int* __restrict__ boff,
                                                      int* __restrict__ rowptr) {
  __shared__ int s[256];
  int i = threadIdx.x;
  int v = (i < NB) ? bsum[i] : 0;
  int val = v;
  s[i] = val;
  __syncthreads();
#pragma unroll
  for (int off = 1; off < 256; off <<= 1) {
    int t = (i >= (unsigned)off) ? s[i - off] : 0;
    __syncthreads();
    val += t;
    s[i] = val;
    __syncthreads();
  }
  if (i < NB) boff[i] = val - v;  // exclusive
  if (i == NB - 1) rowptr[NN] = val;  // total = ET
}

__global__ __launch_bounds__(256) void scan_add_kernel(int* __restrict__ rowptr,
                                                       const int* __restrict__ boff) {
  int i = blockIdx.x * 256 + threadIdx.x;
  if (i < NN) rowptr[i] += boff[blockIdx.x];
}

__global__ void scatter_kernel(const int* __restrict__ ei, const int* __restrict__ rowptr,
                               int* __restrict__ cursor, int* __restrict__ csr_src,
                               int* __restrict__ csr_dst) {
  int e = blockIdx.x * blockDim.x + threadIdx.x;
  if (e >= ET) return;
  int src, dst;
  if (e < E0) { src = ei[e]; dst = ei[E0 + e]; }
  else        { src = e - E0; dst = src; }
  int pos = rowptr[dst] + atomicAdd(&cursor[dst], 1);
  csr_src[pos] = src;
  csr_dst[pos] = dst;
}

// ---------------- GEMM (X @ W) + per-node attention logits ----------------
// Double-buffered LDS + register prefetch: chunk k+1's global loads issue
// before chunk k's compute; one barrier per chunk.
__global__ __launch_bounds__(256, 4) void gemm_att_kernel(
    const float* __restrict__ X, const float* __restrict__ W,
    const float* __restrict__ avs, const float* __restrict__ avd,
    ushort16* __restrict__ hfeat, float* __restrict__ es, float* __restrict__ ed,
    int nnodes)
{
  __shared__ float Ws[2][32][128];   // 32 KB
  __shared__ float XsT[2][32][XS];   // 17.4 KB
  __shared__ float es_s[2][64];
  __shared__ float ed_s[2][64];
  const int tid = threadIdx.x;
  const int n0 = blockIdx.x * 64;
  const int rr = tid & 15, cc = tid >> 4;
  const int r0 = rr * 4, c0 = cc * 4;
  if (tid < 128) { es_s[tid >> 6][tid & 63] = 0.f; ed_s[tid >> 6][tid & 63] = 0.f; }
  float acc[4][8];
#pragma unroll
  for (int i = 0; i < 4; i++)
#pragma unroll
    for (int j = 0; j < 8; j++) acc[i][j] = 0.f;

  const int xnd0 = tid >> 3,          xkk0 = (tid & 7) * 4;
  const int xnd1 = (tid + 256) >> 3,  xkk1 = (tid & 7) * 4;  // (tid+256)&7 == tid&7
  const bool xok0 = (n0 + xnd0) < nnodes;
  const bool xok1 = (n0 + xnd1) < nnodes;

  float4 Wreg[4], Xreg[2];

#define LOAD_CHUNK(KT)                                                          \
  {                                                                             \
    _Pragma("unroll")                                                           \
    for (int i = 0; i < 4; ++i)                                                 \
      Wreg[i] = *(const float4*)&W[(KT) * 128 + (tid + 256 * i) * 4];           \
    Xreg[0] = xok0 ? *(const float4*)&X[(size_t)(n0 + xnd0) * 128 + (KT) + xkk0]\
                   : make_float4(0.f, 0.f, 0.f, 0.f);                           \
    Xreg[1] = xok1 ? *(const float4*)&X[(size_t)(n0 + xnd1) * 128 + (KT) + xkk1]\
                   : make_float4(0.f, 0.f, 0.f, 0.f);                           \
  }

#define STORE_CHUNK(BUF)                                                        \
  {                                                                             \
    float* wf = &Ws[BUF][0][0];                                                 \
    _Pragma("unroll")                                                           \
    for (int i = 0; i < 4; ++i) *(float4*)&wf[(tid + 256 * i) * 4] = Wreg[i];   \
    XsT[BUF][xkk0 + 0][xnd0] = Xreg[0].x; XsT[BUF][xkk0 + 1][xnd0] = Xreg[0].y; \
    XsT[BUF][xkk0 + 2][xnd0] = Xreg[0].z; XsT[BUF][xkk0 + 3][xnd0] = Xreg[0].w; \
    XsT[BUF][xkk1 + 0][xnd1] = Xreg[1].x; XsT[BUF][xkk1 + 1][xnd1] = Xreg[1].y; \
    XsT[BUF][xkk1 + 2][xnd1] = Xreg[1].z; XsT[BUF][xkk1 + 3][xnd1] = Xreg[1].w; \
  }

  LOAD_CHUNK(0)
  STORE_CHUNK(0)
  __syncthreads();

#pragma unroll
  for (int kt = 0; kt < 4; ++kt) {
    const int cur = kt & 1;
    if (kt < 3) LOAD_CHUNK((kt + 1) * 32)
#pragma unroll
    for (int k = 0; k < 32; ++k) {
      float4 xa = *(const float4*)&XsT[cur][k][r0];
      float4 wa = *(const float4*)&Ws[cur][k][c0];
      float4 wb = *(const float4*)&Ws[cur][k][64 + c0];
      float xs[4] = {xa.x, xa.y, xa.z, xa.w};
      float wv[8] = {wa.x, wa.y, wa.z, wa.w, wb.x, wb.y, wb.z, wb.w};
#pragma unroll
      for (int i = 0; i < 4; i++)
#pragma unroll
        for (int j = 0; j < 8; j++) acc[i][j] += xs[i] * wv[j];
    }
    if (kt < 3) {
      STORE_CHUNK(cur ^ 1)
      __syncthreads();
    }
  }

  // attention partials (per head) + bf16 hfeat store
  float as0_[4], as1_[4], ad0_[4], ad1_[4];
#pragma unroll
  for (int j = 0; j < 4; j++) {
    as0_[j] = avs[c0 + j];      ad0_[j] = avd[c0 + j];
    as1_[j] = avs[64 + c0 + j]; ad1_[j] = avd[64 + c0 + j];
  }
#pragma unroll
  for (int i = 0; i < 4; i++) {
    int r = r0 + i;
    int n = n0 + r;
    float ps0 = 0.f, pd0 = 0.f, ps1 = 0.f, pd1 = 0.f;
#pragma unroll
    for (int j = 0; j < 4; j++) {
      ps0 += acc[i][j] * as0_[j];     pd0 += acc[i][j] * ad0_[j];
      ps1 += acc[i][4 + j] * as1_[j]; pd1 += acc[i][4 + j] * ad1_[j];
    }
    atomicAdd(&es_s[0][r], ps0); atomicAdd(&es_s[1][r], ps1);
    atomicAdd(&ed_s[0][r], pd0); atomicAdd(&ed_s[1][r], pd1);
    if (n < nnodes) {
      ushort4 u0, u1;
      u0.x = f2bf(acc[i][0]); u0.y = f2bf(acc[i][1]); u0.z = f2bf(acc[i][2]); u0.w = f2bf(acc[i][3]);
      u1.x = f2bf(acc[i][4]); u1.y = f2bf(acc[i][5]); u1.z = f2bf(acc[i][6]); u1.w = f2bf(acc[i][7]);
      *(ushort4*)&hfeat[(size_t)n * 128 + c0]      = u0;
      *(ushort4*)&hfeat[(size_t)n * 128 + 64 + c0] = u1;
    }
  }
  __syncthreads();
  if (tid < 64) {
    int n = n0 + tid;
    if (n < nnodes) {
      es[n * 2 + 0] = es_s[0][tid]; es[n * 2 + 1] = es_s[1][tid];
      ed[n * 2 + 0] = ed_s[0][tid]; ed[n * 2 + 1] = ed_s[1][tid];
    }
  }
#undef LOAD_CHUNK
#undef STORE_CHUNK
}

// ---------------- per-edge softmax weights (both heads) ----------------
__global__ __launch_bounds__(256) void edge_w_kernel(
    const float* __restrict__ es, const float* __restrict__ ed,
    const int* __restrict__ csr_src, const int* __restrict__ csr_dst,
    float2* __restrict__ wbuf)
{
  int i = blockIdx.x * 256 + threadIdx.x;
  if (i >= ET) return;
  int s = csr_src[i], d = csr_dst[i];
  float2 esv = ((const float2*)es)[s];
  float2 edv = ((const float2*)ed)[d];
  float e0 = esv.x + edv.x, e1 = esv.y + edv.y;
  e0 = (e0 > 0.f) ? e0 : 0.2f * e0;
  e1 = (e1 > 0.f) ? e1 : 0.2f * e1;
  wbuf[i] = make_float2(__expf(e0), __expf(e1));
}

// ---------------- aggregation: one wave per node ----------------
__global__ __launch_bounds__(256) void aggregate_kernel(
    const uint32* __restrict__ hfeat, const float2* __restrict__ wbuf,
    const int* __restrict__ rowptr, const int* __restrict__ csr_src,
    const float* __restrict__ bias, float* __restrict__ out, int nnodes)
{
  int n = (blockIdx.x * blockDim.x + threadIdx.x) >> 6;
  int lane = threadIdx.x & 63;
  if (n >= nnodes) return;
  int beg = rowptr[n], end = rowptr[n + 1];
  const bool hi = lane >= 32;
  float accE = 0.f, accO = 0.f, den = 0.f;

  int idxA[4]; float wA[4];
  int i = beg;
#pragma unroll
  for (int t = 0; t < 4; ++t) {
    int j = i + t;
    int jj = (j < end) ? j : beg;
    idxA[t] = csr_src[jj];
    float2 ww = wbuf[jj];
    float w = hi ? ww.y : ww.x;
    wA[t] = (j < end) ? w : 0.f;
  }
  i += 4;
  for (;;) {
    bool more = (i < end);
    int idxB[4]; float wB[4];
    if (more) {
#pragma unroll
      for (int t = 0; t < 4; ++t) {
        int j = i + t;
        int jj = (j < end) ? j : beg;
        idxB[t] = csr_src[jj];
        float2 ww = wbuf[jj];
        float w = hi ? ww.y : ww.x;
        wB[t] = (j < end) ? w : 0.f;
      }
    }
    uint32 hv[4];
#pragma unroll
    for (int t = 0; t < 4; ++t) hv[t] = hfeat[(size_t)idxA[t] * 64 + lane];
#pragma unroll
    for (int t = 0; t < 4; ++t) {
      float fe = __uint_as_float(hv[t] << 16);
      float fo = __uint_as_float(hv[t] & 0xFFFF0000u);
      accE = fmaf(wA[t], fe, accE);
      accO = fmaf(wA[t], fo, accO);
      den += wA[t];
    }
    if (!more) break;
#pragma unroll
    for (int t = 0; t < 4; ++t) { idxA[t] = idxB[t]; wA[t] = wB[t]; }
    i += 4;
  }
  float inv = 1.f / den;
  int m = lane & 31;
  int off = hi ? 64 : 0;
  float2 bb = *(const float2*)&bias[off + 2 * m];
  float v0 = accE * inv + bb.x;
  float v1 = accO * inv + bb.y;
  v0 = (v0 > 0.f) ? v0 : (__expf(v0) - 1.f);
  v1 = (v1 > 0.f) ? v1 : (__expf(v1) - 1.f);
  *(float2*)&out[(size_t)n * 128 + off + 2 * m] = make_float2(v0, v1);
}

// ---------------- final linear (256->40) + log_softmax, tiled GEMM ----------------
__global__ __launch_bounds__(256) void final_kernel(
    const float* __restrict__ h1, const float* __restrict__ h2,
    const float* __restrict__ lw, const float* __restrict__ lb,
    float* __restrict__ out, int nnodes)
{
  __shared__ __align__(16) float Hs[64][33];
  __shared__ __align__(16) float Ws2[32 * 40];
  const int tid = threadIdx.x;
  const int m = tid >> 2, q = tid & 3;
  const int n0 = blockIdx.x * 64;

  float bj[10];
#pragma unroll
  for (int j = 0; j < 10; ++j) bj[j] = lb[q * 10 + j];

  float acc[10];
#pragma unroll
  for (int j = 0; j < 10; ++j) acc[j] = 0.f;

  for (int kc = 0; kc < 256; kc += 32) {
    __syncthreads();
#pragma unroll
    for (int it = 0; it < 2; ++it) {
      int idx = tid + it * 256;
      int nd = idx >> 3, kk = (idx & 7) * 4;
      int n = n0 + nd;
      float4 v = make_float4(0.f, 0.f, 0.f, 0.f);
      if (n < nnodes) {
        const float* src = (kc < 128) ? &h1[(size_t)n * 128 + kc + kk]
                                      : &h2[(size_t)n * 128 + (kc - 128) + kk];
        v = *(const float4*)src;
      }
      Hs[nd][kk + 0] = v.x; Hs[nd][kk + 1] = v.y;
      Hs[nd][kk + 2] = v.z; Hs[nd][kk + 3] = v.w;
    }
    {
      float4 v = *(const float4*)&lw[kc * 40 + tid * 4];
      *(float4*)&Ws2[tid * 4] = v;
      if (tid < 64) {
        float4 v2 = *(const float4*)&lw[kc * 40 + (256 + tid) * 4];
        *(float4*)&Ws2[(256 + tid) * 4] = v2;
      }
    }
    __syncthreads();
#pragma unroll
    for (int k = 0; k < 32; ++k) {
      float a = Hs[m][k];
      const float* wr = &Ws2[k * 40 + q * 10];
#pragma unroll
      for (int j = 0; j < 10; ++j) acc[j] = fmaf(a, wr[j], acc[j]);
    }
  }

  float mx = -INFINITY;
#pragma unroll
  for (int j = 0; j < 10; ++j) { acc[j] += bj[j]; mx = fmaxf(mx, acc[j]); }
  mx = fmaxf(mx, __shfl_xor(mx, 1));
  mx = fmaxf(mx, __shfl_xor(mx, 2));
  float s = 0.f;
#pragma unroll
  for (int j = 0; j < 10; ++j) s += __expf(acc[j] - mx);
  s += __shfl_xor(s, 1);
  s += __shfl_xor(s, 2);
  float lg = mx + __logf(s);
  int n = n0 + m;
  if (n < nnodes) {
#pragma unroll
    for (int j = 0; j < 10; ++j) out[(size_t)n * 40 + q * 10 + j] = acc[j] - lg;
  }
}

// ---------------- launch ----------------

extern "C" void kernel_launch(void* const* d_in, const int* in_sizes, int n_in,
                              void* d_out, int out_size, void* d_ws, size_t ws_size,
                              hipStream_t stream) {
  const float* x   = (const float*)d_in[0];
  const int*   ei  = (const int*)d_in[1];
  const float* W0  = (const float*)d_in[2];
  const float* as0 = (const float*)d_in[3];
  const float* ad0 = (const float*)d_in[4];
  const float* b0  = (const float*)d_in[5];
  const float* W1  = (const float*)d_in[6];
  const float* as1 = (const float*)d_in[7];
  const float* ad1 = (const float*)d_in[8];
  const float* b1  = (const float*)d_in[9];
  const float* lw  = (const float*)d_in[10];
  const float* lb  = (const float*)d_in[11];
  float* out = (float*)d_out;

  char* p = (char*)d_ws;
  auto carve = [&](size_t bytes) { char* r = p; p += (bytes + 255) & ~(size_t)255; return r; };
  ushort16* hfeat = (ushort16*)carve((size_t)NN * 128 * 2);  // bf16
  float* h1o   = (float*)carve((size_t)NN * 128 * 4);
  float* h2o   = (float*)carve((size_t)NN * 128 * 4);
  float* es    = (float*)carve((size_t)NN * 2 * 4);
  float* ed    = (float*)carve((size_t)NN * 2 * 4);
  int* rowptr  = (int*)carve((size_t)(NN + 1) * 4);
  int* cnt     = (int*)carve((size_t)NN * 4);
  int* csr     = (int*)carve((size_t)ET * 4);
  int* csrd    = (int*)carve((size_t)ET * 4);
  float2* wbuf = (float2*)carve((size_t)ET * 8);
  int* bsum    = (int*)carve((size_t)NB * 4);
  int* boff    = (int*)carve((size_t)NB * 4);

  // CSR build (reused by both layers)
  zero_int_kernel<<<(NN + 1023) / 1024, 1024, 0, stream>>>(cnt, NN);
  count_kernel<<<(ET + 255) / 256, 256, 0, stream>>>(ei, cnt);
  scan_l1_kernel<<<NB, 256, 0, stream>>>(cnt, rowptr, bsum);
  scan_l2_kernel<<<1, 256, 0, stream>>>(bsum, boff, rowptr);
  scan_add_kernel<<<NB, 256, 0, stream>>>(rowptr, boff);
  zero_int_kernel<<<(NN + 1023) / 1024, 1024, 0, stream>>>(cnt, NN);
  scatter_kernel<<<(ET + 255) / 256, 256, 0, stream>>>(ei, rowptr, cnt, csr, csrd);

  // layer 1
  gemm_att_kernel<<<(NN + 63) / 64, 256, 0, stream>>>(x, W0, as0, ad0, hfeat, es, ed, NN);
  edge_w_kernel<<<(ET + 255) / 256, 256, 0, stream>>>(es, ed, csr, csrd, wbuf);
  aggregate_kernel<<<(NN * 64 + 255) / 256, 256, 0, stream>>>((const uint32*)hfeat, wbuf, rowptr, csr, b0, h1o, NN);
  // layer 2
  gemm_att_kernel<<<(NN + 63) / 64, 256, 0, stream>>>(h1o, W1, as1, ad1, hfeat, es, ed, NN);
  edge_w_kernel<<<(ET + 255) / 256, 256, 0, stream>>>(es, ed, csr, csrd, wbuf);
  aggregate_kernel<<<(NN * 64 + 255) / 256, 256, 0, stream>>>((const uint32*)hfeat, wbuf, rowptr, csr, b1, h2o, NN);
  // head
  final_kernel<<<(NN + 63) / 64, 256, 0, stream>>>(h1o, h2o, lw, lb, out, NN);
}

// Round 7
// 470.400 us; speedup vs baseline: 7.6784x; 7.6784x over previous
//
#include <hip/hip_runtime.h>
#include <math.h>

#define NN 50000
#define E0 800000
#define ET 850000
#define NB 196  // ceil(NN/256) scan blocks
#define XS 68   // XsT row stride: 4*68 mod 32 = 16 -> 4-way store conflicts

typedef unsigned int uint32;
typedef unsigned short ushort16;

__device__ __forceinline__ ushort16 f2bf(float f) {
  uint32 u = __float_as_uint(f);
  return (ushort16)((u + 0x7FFFu + ((u >> 16) & 1u)) >> 16);  // RNE
}

// ---------------- CSR build ----------------

__global__ void zero_int_kernel(int* __restrict__ p, int n) {
  int i = blockIdx.x * blockDim.x + threadIdx.x;
  if (i < n) p[i] = 0;
}

__global__ void count_kernel(const int* __restrict__ ei, int* __restrict__ cnt) {
  int e = blockIdx.x * blockDim.x + threadIdx.x;
  if (e >= ET) return;
  int dst = (e < E0) ? ei[E0 + e] : (e - E0);
  atomicAdd(&cnt[dst], 1);
}

__global__ __launch_bounds__(256) void scan_l1_kernel(const int* __restrict__ cnt,
                                                      int* __restrict__ rowptr,
                                                      int* __restrict__ bsum) {
  __shared__ int s[256];
  int i = blockIdx.x * 256 + threadIdx.x;
  int v = (i < NN) ? cnt[i] : 0;
  int val = v;
  s[threadIdx.x] = val;
  __syncthreads();
#pragma unroll
  for (int off = 1; off < 256; off <<= 1) {
    int t = (threadIdx.x >= (unsigned)off) ? s[threadIdx.x - off] : 0;
    __syncthreads();
    val += t;
    s[threadIdx.x] = val;
    __syncthreads();
  }
  if (i < NN) rowptr[i] = val - v;  // block-local exclusive
  if (threadIdx.x == 255) bsum[blockIdx.x] = val;
}

__global__ __launch_bounds__(256) void scan_l2_kernel(const int* __restrict__ bsum,
                                                      int* __restrict__ boff,
                                                      int* __restrict__ rowptr) {
  __shared__ int s[256];
  int i = threadIdx.x;
  int v = (i < NB) ? bsum[i] : 0;
  int val = v;
  s[i] = val;
  __syncthreads();
#pragma unroll
  for (int off = 1; off < 256; off <<= 1) {
    int t = (i >= (unsigned)off) ? s[i - off] : 0;
    __syncthreads();
    val += t;
    s[i] = val;
    __syncthreads();
  }
  if (i < NB) boff[i] = val - v;  // exclusive
  if (i == NB - 1) rowptr[NN] = val;  // total = ET
}

__global__ __launch_bounds__(256) void scan_add_kernel(int* __restrict__ rowptr,
                                                       const int* __restrict__ boff) {
  int i = blockIdx.x * 256 + threadIdx.x;
  if (i < NN) rowptr[i] += boff[blockIdx.x];
}

__global__ void scatter_kernel(const int* __restrict__ ei, const int* __restrict__ rowptr,
                               int* __restrict__ cursor, int* __restrict__ csr_src,
                               int* __restrict__ csr_dst) {
  int e = blockIdx.x * blockDim.x + threadIdx.x;
  if (e >= ET) return;
  int src, dst;
  if (e < E0) { src = ei[e]; dst = ei[E0 + e]; }
  else        { src = e - E0; dst = src; }
  int pos = rowptr[dst] + atomicAdd(&cursor[dst], 1);
  csr_src[pos] = src;
  csr_dst[pos] = dst;
}

// ---------------- GEMM (X @ W) + per-node attention logits ----------------
// Double-buffered LDS pipeline, sequential chunks (#pragma unroll 1 keeps
// exactly one Wreg/Xreg set live -> no spill; round-6's full unroll spilled).
__global__ __launch_bounds__(256) void gemm_att_kernel(
    const float* __restrict__ X, const float* __restrict__ W,
    const float* __restrict__ avs, const float* __restrict__ avd,
    ushort16* __restrict__ hfeat, float* __restrict__ es, float* __restrict__ ed,
    int nnodes)
{
  __shared__ float Ws[2][32][128];   // 32 KB
  __shared__ float XsT[2][32][XS];   // 17.4 KB
  __shared__ float es_s[2][64];
  __shared__ float ed_s[2][64];
  const int tid = threadIdx.x;
  const int n0 = blockIdx.x * 64;
  const int rr = tid & 15, cc = tid >> 4;
  const int r0 = rr * 4, c0 = cc * 4;
  if (tid < 128) { es_s[tid >> 6][tid & 63] = 0.f; ed_s[tid >> 6][tid & 63] = 0.f; }
  float acc[4][8];
#pragma unroll
  for (int i = 0; i < 4; i++)
#pragma unroll
    for (int j = 0; j < 8; j++) acc[i][j] = 0.f;

  const int xnd0 = tid >> 3,          xkk0 = (tid & 7) * 4;
  const int xnd1 = (tid + 256) >> 3,  xkk1 = (tid & 7) * 4;
  const bool xok0 = (n0 + xnd0) < nnodes;
  const bool xok1 = (n0 + xnd1) < nnodes;

  float4 Wreg[4], Xreg[2];

#define LOAD_CHUNK(KT)                                                          \
  {                                                                             \
    _Pragma("unroll")                                                           \
    for (int i = 0; i < 4; ++i)                                                 \
      Wreg[i] = *(const float4*)&W[(KT) * 128 + (tid + 256 * i) * 4];           \
    Xreg[0] = xok0 ? *(const float4*)&X[(size_t)(n0 + xnd0) * 128 + (KT) + xkk0]\
                   : make_float4(0.f, 0.f, 0.f, 0.f);                           \
    Xreg[1] = xok1 ? *(const float4*)&X[(size_t)(n0 + xnd1) * 128 + (KT) + xkk1]\
                   : make_float4(0.f, 0.f, 0.f, 0.f);                           \
  }

#define STORE_CHUNK(BUF)                                                        \
  {                                                                             \
    float* wf = &Ws[BUF][0][0];                                                 \
    _Pragma("unroll")                                                           \
    for (int i = 0; i < 4; ++i) *(float4*)&wf[(tid + 256 * i) * 4] = Wreg[i];   \
    XsT[BUF][xkk0 + 0][xnd0] = Xreg[0].x; XsT[BUF][xkk0 + 1][xnd0] = Xreg[0].y; \
    XsT[BUF][xkk0 + 2][xnd0] = Xreg[0].z; XsT[BUF][xkk0 + 3][xnd0] = Xreg[0].w; \
    XsT[BUF][xkk1 + 0][xnd1] = Xreg[1].x; XsT[BUF][xkk1 + 1][xnd1] = Xreg[1].y; \
    XsT[BUF][xkk1 + 2][xnd1] = Xreg[1].z; XsT[BUF][xkk1 + 3][xnd1] = Xreg[1].w; \
  }

  LOAD_CHUNK(0)
  STORE_CHUNK(0)
  __syncthreads();

  int cur = 0;
#pragma unroll 1
  for (int kt = 0; kt < 128; kt += 32) {
    const bool notlast = (kt < 96);
    if (notlast) LOAD_CHUNK(kt + 32)      // in flight during compute
#pragma unroll
    for (int k = 0; k < 32; ++k) {
      float4 xa = *(const float4*)&XsT[cur][k][r0];
      float4 wa = *(const float4*)&Ws[cur][k][c0];
      float4 wb = *(const float4*)&Ws[cur][k][64 + c0];
      float xs[4] = {xa.x, xa.y, xa.z, xa.w};
      float wv[8] = {wa.x, wa.y, wa.z, wa.w, wb.x, wb.y, wb.z, wb.w};
#pragma unroll
      for (int i = 0; i < 4; i++)
#pragma unroll
        for (int j = 0; j < 8; j++) acc[i][j] += xs[i] * wv[j];
    }
    if (notlast) {
      STORE_CHUNK(cur ^ 1)
      __syncthreads();
      cur ^= 1;
    }
  }

  // attention partials (per head) + bf16 hfeat store
  float as0_[4], as1_[4], ad0_[4], ad1_[4];
#pragma unroll
  for (int j = 0; j < 4; j++) {
    as0_[j] = avs[c0 + j];      ad0_[j] = avd[c0 + j];
    as1_[j] = avs[64 + c0 + j]; ad1_[j] = avd[64 + c0 + j];
  }
#pragma unroll
  for (int i = 0; i < 4; i++) {
    int r = r0 + i;
    int n = n0 + r;
    float ps0 = 0.f, pd0 = 0.f, ps1 = 0.f, pd1 = 0.f;
#pragma unroll
    for (int j = 0; j < 4; j++) {
      ps0 += acc[i][j] * as0_[j];     pd0 += acc[i][j] * ad0_[j];
      ps1 += acc[i][4 + j] * as1_[j]; pd1 += acc[i][4 + j] * ad1_[j];
    }
    atomicAdd(&es_s[0][r], ps0); atomicAdd(&es_s[1][r], ps1);
    atomicAdd(&ed_s[0][r], pd0); atomicAdd(&ed_s[1][r], pd1);
    if (n < nnodes) {
      ushort4 u0, u1;
      u0.x = f2bf(acc[i][0]); u0.y = f2bf(acc[i][1]); u0.z = f2bf(acc[i][2]); u0.w = f2bf(acc[i][3]);
      u1.x = f2bf(acc[i][4]); u1.y = f2bf(acc[i][5]); u1.z = f2bf(acc[i][6]); u1.w = f2bf(acc[i][7]);
      *(ushort4*)&hfeat[(size_t)n * 128 + c0]      = u0;
      *(ushort4*)&hfeat[(size_t)n * 128 + 64 + c0] = u1;
    }
  }
  __syncthreads();
  if (tid < 64) {
    int n = n0 + tid;
    if (n < nnodes) {
      es[n * 2 + 0] = es_s[0][tid]; es[n * 2 + 1] = es_s[1][tid];
      ed[n * 2 + 0] = ed_s[0][tid]; ed[n * 2 + 1] = ed_s[1][tid];
    }
  }
#undef LOAD_CHUNK
#undef STORE_CHUNK
}

// ---------------- per-edge softmax weights (both heads) ----------------
__global__ __launch_bounds__(256) void edge_w_kernel(
    const float* __restrict__ es, const float* __restrict__ ed,
    const int* __restrict__ csr_src, const int* __restrict__ csr_dst,
    float2* __restrict__ wbuf)
{
  int i = blockIdx.x * 256 + threadIdx.x;
  if (i >= ET) return;
  int s = csr_src[i], d = csr_dst[i];
  float2 esv = ((const float2*)es)[s];
  float2 edv = ((const float2*)ed)[d];
  float e0 = esv.x + edv.x, e1 = esv.y + edv.y;
  e0 = (e0 > 0.f) ? e0 : 0.2f * e0;
  e1 = (e1 > 0.f) ? e1 : 0.2f * e1;
  wbuf[i] = make_float2(__expf(e0), __expf(e1));
}

// ---------------- aggregation: one wave per node ----------------
__global__ __launch_bounds__(256) void aggregate_kernel(
    const uint32* __restrict__ hfeat, const float2* __restrict__ wbuf,
    const int* __restrict__ rowptr, const int* __restrict__ csr_src,
    const float* __restrict__ bias, float* __restrict__ out, int nnodes)
{
  int n = (blockIdx.x * blockDim.x + threadIdx.x) >> 6;
  int lane = threadIdx.x & 63;
  if (n >= nnodes) return;
  int beg = rowptr[n], end = rowptr[n + 1];
  const bool hi = lane >= 32;
  float accE = 0.f, accO = 0.f, den = 0.f;

  int idxA[4]; float wA[4];
  int i = beg;
#pragma unroll
  for (int t = 0; t < 4; ++t) {
    int j = i + t;
    int jj = (j < end) ? j : beg;
    idxA[t] = csr_src[jj];
    float2 ww = wbuf[jj];
    float w = hi ? ww.y : ww.x;
    wA[t] = (j < end) ? w : 0.f;
  }
  i += 4;
  for (;;) {
    bool more = (i < end);
    int idxB[4]; float wB[4];
    if (more) {
#pragma unroll
      for (int t = 0; t < 4; ++t) {
        int j = i + t;
        int jj = (j < end) ? j : beg;
        idxB[t] = csr_src[jj];
        float2 ww = wbuf[jj];
        float w = hi ? ww.y : ww.x;
        wB[t] = (j < end) ? w : 0.f;
      }
    }
    uint32 hv[4];
#pragma unroll
    for (int t = 0; t < 4; ++t) hv[t] = hfeat[(size_t)idxA[t] * 64 + lane];
#pragma unroll
    for (int t = 0; t < 4; ++t) {
      float fe = __uint_as_float(hv[t] << 16);
      float fo = __uint_as_float(hv[t] & 0xFFFF0000u);
      accE = fmaf(wA[t], fe, accE);
      accO = fmaf(wA[t], fo, accO);
      den += wA[t];
    }
    if (!more) break;
#pragma unroll
    for (int t = 0; t < 4; ++t) { idxA[t] = idxB[t]; wA[t] = wB[t]; }
    i += 4;
  }
  float inv = 1.f / den;
  int m = lane & 31;
  int off = hi ? 64 : 0;
  float2 bb = *(const float2*)&bias[off + 2 * m];
  float v0 = accE * inv + bb.x;
  float v1 = accO * inv + bb.y;
  v0 = (v0 > 0.f) ? v0 : (__expf(v0) - 1.f);
  v1 = (v1 > 0.f) ? v1 : (__expf(v1) - 1.f);
  *(float2*)&out[(size_t)n * 128 + off + 2 * m] = make_float2(v0, v1);
}

// ---------------- final linear (256->40) + log_softmax, tiled GEMM ----------------
__global__ __launch_bounds__(256) void final_kernel(
    const float* __restrict__ h1, const float* __restrict__ h2,
    const float* __restrict__ lw, const float* __restrict__ lb,
    float* __restrict__ out, int nnodes)
{
  __shared__ __align__(16) float Hs[64][33];
  __shared__ __align__(16) float Ws2[32 * 40];
  const int tid = threadIdx.x;
  const int m = tid >> 2, q = tid & 3;
  const int n0 = blockIdx.x * 64;

  float bj[10];
#pragma unroll
  for (int j = 0; j < 10; ++j) bj[j] = lb[q * 10 + j];

  float acc[10];
#pragma unroll
  for (int j = 0; j < 10; ++j) acc[j] = 0.f;

  for (int kc = 0; kc < 256; kc += 32) {
    __syncthreads();
#pragma unroll
    for (int it = 0; it < 2; ++it) {
      int idx = tid + it * 256;
      int nd = idx >> 3, kk = (idx & 7) * 4;
      int n = n0 + nd;
      float4 v = make_float4(0.f, 0.f, 0.f, 0.f);
      if (n < nnodes) {
        const float* src = (kc < 128) ? &h1[(size_t)n * 128 + kc + kk]
                                      : &h2[(size_t)n * 128 + (kc - 128) + kk];
        v = *(const float4*)src;
      }
      Hs[nd][kk + 0] = v.x; Hs[nd][kk + 1] = v.y;
      Hs[nd][kk + 2] = v.z; Hs[nd][kk + 3] = v.w;
    }
    {
      float4 v = *(const float4*)&lw[kc * 40 + tid * 4];
      *(float4*)&Ws2[tid * 4] = v;
      if (tid < 64) {
        float4 v2 = *(const float4*)&lw[kc * 40 + (256 + tid) * 4];
        *(float4*)&Ws2[(256 + tid) * 4] = v2;
      }
    }
    __syncthreads();
#pragma unroll
    for (int k = 0; k < 32; ++k) {
      float a = Hs[m][k];
      const float* wr = &Ws2[k * 40 + q * 10];
#pragma unroll
      for (int j = 0; j < 10; ++j) acc[j] = fmaf(a, wr[j], acc[j]);
    }
  }

  float mx = -INFINITY;
#pragma unroll
  for (int j = 0; j < 10; ++j) { acc[j] += bj[j]; mx = fmaxf(mx, acc[j]); }
  mx = fmaxf(mx, __shfl_xor(mx, 1));
  mx = fmaxf(mx, __shfl_xor(mx, 2));
  float s = 0.f;
#pragma unroll
  for (int j = 0; j < 10; ++j) s += __expf(acc[j] - mx);
  s += __shfl_xor(s, 1);
  s += __shfl_xor(s, 2);
  float lg = mx + __logf(s);
  int n = n0 + m;
  if (n < nnodes) {
#pragma unroll
    for (int j = 0; j < 10; ++j) out[(size_t)n * 40 + q * 10 + j] = acc[j] - lg;
  }
}

// ---------------- launch ----------------

extern "C" void kernel_launch(void* const* d_in, const int* in_sizes, int n_in,
                              void* d_out, int out_size, void* d_ws, size_t ws_size,
                              hipStream_t stream) {
  const float* x   = (const float*)d_in[0];
  const int*   ei  = (const int*)d_in[1];
  const float* W0  = (const float*)d_in[2];
  const float* as0 = (const float*)d_in[3];
  const float* ad0 = (const float*)d_in[4];
  const float* b0  = (const float*)d_in[5];
  const float* W1  = (const float*)d_in[6];
  const float* as1 = (const float*)d_in[7];
  const float* ad1 = (const float*)d_in[8];
  const float* b1  = (const float*)d_in[9];
  const float* lw  = (const float*)d_in[10];
  const float* lb  = (const float*)d_in[11];
  float* out = (float*)d_out;

  char* p = (char*)d_ws;
  auto carve = [&](size_t bytes) { char* r = p; p += (bytes + 255) & ~(size_t)255; return r; };
  ushort16* hfeat = (ushort16*)carve((size_t)NN * 128 * 2);  // bf16
  float* h1o   = (float*)carve((size_t)NN * 128 * 4);
  float* h2o   = (float*)carve((size_t)NN * 128 * 4);
  float* es    = (float*)carve((size_t)NN * 2 * 4);
  float* ed    = (float*)carve((size_t)NN * 2 * 4);
  int* rowptr  = (int*)carve((size_t)(NN + 1) * 4);
  int* cnt     = (int*)carve((size_t)NN * 4);
  int* csr     = (int*)carve((size_t)ET * 4);
  int* csrd    = (int*)carve((size_t)ET * 4);
  float2* wbuf = (float2*)carve((size_t)ET * 8);
  int* bsum    = (int*)carve((size_t)NB * 4);
  int* boff    = (int*)carve((size_t)NB * 4);

  // CSR build (reused by both layers)
  zero_int_kernel<<<(NN + 1023) / 1024, 1024, 0, stream>>>(cnt, NN);
  count_kernel<<<(ET + 255) / 256, 256, 0, stream>>>(ei, cnt);
  scan_l1_kernel<<<NB, 256, 0, stream>>>(cnt, rowptr, bsum);
  scan_l2_kernel<<<1, 256, 0, stream>>>(bsum, boff, rowptr);
  scan_add_kernel<<<NB, 256, 0, stream>>>(rowptr, boff);
  zero_int_kernel<<<(NN + 1023) / 1024, 1024, 0, stream>>>(cnt, NN);
  scatter_kernel<<<(ET + 255) / 256, 256, 0, stream>>>(ei, rowptr, cnt, csr, csrd);

  // layer 1
  gemm_att_kernel<<<(NN + 63) / 64, 256, 0, stream>>>(x, W0, as0, ad0, hfeat, es, ed, NN);
  edge_w_kernel<<<(ET + 255) / 256, 256, 0, stream>>>(es, ed, csr, csrd, wbuf);
  aggregate_kernel<<<(NN * 64 + 255) / 256, 256, 0, stream>>>((const uint32*)hfeat, wbuf, rowptr, csr, b0, h1o, NN);
  // layer 2
  gemm_att_kernel<<<(NN + 63) / 64, 256, 0, stream>>>(h1o, W1, as1, ad1, hfeat, es, ed, NN);
  edge_w_kernel<<<(ET + 255) / 256, 256, 0, stream>>>(es, ed, csr, csrd, wbuf);
  aggregate_kernel<<<(NN * 64 + 255) / 256, 256, 0, stream>>>((const uint32*)hfeat, wbuf, rowptr, csr, b1, h2o, NN);
  // head
  final_kernel<<<(NN + 63) / 64, 256, 0, stream>>>(h1o, h2o, lw, lb, out, NN);
}

// Round 8
// 436.275 us; speedup vs baseline: 8.2790x; 1.0782x over previous
//
#include <hip/hip_runtime.h>
#include <math.h>

#define NN 50000
#define E0 800000
#define ET 850000
#define NB 196   // ceil(NN/256) scan blocks
#define NBX 200  // prep: x-conversion blocks (+2 for W transposes)

typedef unsigned int uint32;
typedef unsigned short u16;
typedef __attribute__((ext_vector_type(8))) short bf16x8;  // 8 bf16 = 4 VGPRs
typedef __attribute__((ext_vector_type(4))) float f32x4;

__device__ __forceinline__ u16 f2bf(float f) {
  uint32 u = __float_as_uint(f);
  return (u16)((u + 0x7FFFu + ((u >> 16) & 1u)) >> 16);  // RNE
}
__device__ __forceinline__ float bflo(uint32 u) { return __uint_as_float(u << 16); }
__device__ __forceinline__ float bfhi(uint32 u) { return __uint_as_float(u & 0xFFFF0000u); }

// ---------------- prep: x -> bf16; W0,W1 -> bf16 transposed [n][k] ----------------
__global__ __launch_bounds__(256) void prep_kernel(
    const float* __restrict__ x, const float* __restrict__ W0, const float* __restrict__ W1,
    u16* __restrict__ xb, u16* __restrict__ w0t, u16* __restrict__ w1t)
{
  int b = blockIdx.x;
  if (b < NBX) {
    const float4* x4 = (const float4*)x;
    ushort4* xb4 = (ushort4*)xb;
    const int total = NN * 128 / 4;
    for (int i = b * 256 + threadIdx.x; i < total; i += NBX * 256) {
      float4 v = x4[i];
      ushort4 u;
      u.x = f2bf(v.x); u.y = f2bf(v.y); u.z = f2bf(v.z); u.w = f2bf(v.w);
      xb4[i] = u;
    }
  } else {
    const float* W = (b == NBX) ? W0 : W1;
    u16* Wt = (b == NBX) ? w0t : w1t;
    __shared__ float tile[32][129];
    const int tid = threadIdx.x;
    for (int k0 = 0; k0 < 128; k0 += 32) {
      __syncthreads();
#pragma unroll
      for (int it = 0; it < 4; ++it) {  // 32 k-rows x 128 n, coalesced
        int q = tid + it * 256;
        int kk = q >> 5, n4 = (q & 31) * 4;
        float4 v = *(const float4*)&W[(k0 + kk) * 128 + n4];
        tile[kk][n4 + 0] = v.x; tile[kk][n4 + 1] = v.y;
        tile[kk][n4 + 2] = v.z; tile[kk][n4 + 3] = v.w;
      }
      __syncthreads();
      int n = tid >> 1, h = (tid & 1) * 16;
      __align__(16) u16 tmp[16];
#pragma unroll
      for (int j = 0; j < 16; ++j) tmp[j] = f2bf(tile[h + j][n]);
      *(uint4*)&Wt[n * 128 + k0 + h] = *(uint4*)&tmp[0];
      *(uint4*)&Wt[n * 128 + k0 + h + 8] = *(uint4*)&tmp[8];
    }
  }
}

// ---------------- CSR build ----------------

__global__ void zero_int_kernel(int* __restrict__ p, int n) {
  int i = blockIdx.x * blockDim.x + threadIdx.x;
  if (i < n) p[i] = 0;
}

__global__ void count_kernel(const int* __restrict__ ei, int* __restrict__ cnt) {
  int e = blockIdx.x * blockDim.x + threadIdx.x;
  if (e >= ET) return;
  int dst = (e < E0) ? ei[E0 + e] : (e - E0);
  atomicAdd(&cnt[dst], 1);
}

__global__ __launch_bounds__(256) void scan_l1_kernel(const int* __restrict__ cnt,
                                                      int* __restrict__ rowptr,
                                                      int* __restrict__ bsum) {
  __shared__ int s[256];
  int i = blockIdx.x * 256 + threadIdx.x;
  int v = (i < NN) ? cnt[i] : 0;
  int val = v;
  s[threadIdx.x] = val;
  __syncthreads();
#pragma unroll
  for (int off = 1; off < 256; off <<= 1) {
    int t = (threadIdx.x >= (unsigned)off) ? s[threadIdx.x - off] : 0;
    __syncthreads();
    val += t;
    s[threadIdx.x] = val;
    __syncthreads();
  }
  if (i < NN) rowptr[i] = val - v;
  if (threadIdx.x == 255) bsum[blockIdx.x] = val;
}

__global__ __launch_bounds__(256) void scan_l2_kernel(const int* __restrict__ bsum,
                                                      int* __restrict__ boff,
                                                      int* __restrict__ rowptr) {
  __shared__ int s[256];
  int i = threadIdx.x;
  int v = (i < NB) ? bsum[i] : 0;
  int val = v;
  s[i] = val;
  __syncthreads();
#pragma unroll
  for (int off = 1; off < 256; off <<= 1) {
    int t = (i >= (unsigned)off) ? s[i - off] : 0;
    __syncthreads();
    val += t;
    s[i] = val;
    __syncthreads();
  }
  if (i < NB) boff[i] = val - v;
  if (i == NB - 1) rowptr[NN] = val;
}

__global__ __launch_bounds__(256) void scan_add_kernel(int* __restrict__ rowptr,
                                                       const int* __restrict__ boff) {
  int i = blockIdx.x * 256 + threadIdx.x;
  if (i < NN) rowptr[i] += boff[blockIdx.x];
}

__global__ void scatter_kernel(const int* __restrict__ ei, const int* __restrict__ rowptr,
                               int* __restrict__ cursor, int* __restrict__ csr_src,
                               int* __restrict__ csr_dst) {
  int e = blockIdx.x * blockDim.x + threadIdx.x;
  if (e >= ET) return;
  int src, dst;
  if (e < E0) { src = ei[e]; dst = ei[E0 + e]; }
  else        { src = e - E0; dst = src; }
  int pos = rowptr[dst] + atomicAdd(&cursor[dst], 1);
  csr_src[pos] = src;
  csr_dst[pos] = dst;
}

// ---------------- MFMA GEMM (Xb @ W) + attention logits ----------------
// 64-node x 128-col tile, bf16 inputs staged once in LDS (one barrier pair).
// Wave w computes rows 16w..16w+15, all 128 cols: 8 N-tiles x 4 K-steps of
// v_mfma_f32_16x16x32_bf16. A: m=lane&15,k=quad*8+j; C/D: col=lane&15,row=quad*4+reg.
__global__ __launch_bounds__(256) void gemm_att_kernel(
    const u16* __restrict__ Xb, const u16* __restrict__ Wt,
    const float* __restrict__ avs, const float* __restrict__ avd,
    u16* __restrict__ hfeat, float* __restrict__ es, float* __restrict__ ed,
    int nnodes)
{
  __shared__ u16 Xs[64 * 136];    // 17.0 KB, padded stride 136
  __shared__ u16 Ws[128 * 136];   // 34.0 KB (reused as bf16 out-staging)
  __shared__ float es_s[2][64];
  __shared__ float ed_s[2][64];
  const int tid = threadIdx.x;
  const int wid = tid >> 6, lane = tid & 63;
  const int quad = lane >> 4, lc = lane & 15;
  const int n0 = blockIdx.x * 64;
  if (tid < 128) { es_s[tid >> 6][tid & 63] = 0.f; ed_s[tid >> 6][tid & 63] = 0.f; }

#pragma unroll
  for (int it = 0; it < 4; ++it) {    // Xs: 64 x 128 bf16
    int g = tid + it * 256;
    int r = g >> 4, c8 = (g & 15) * 8;
    uint4 v = make_uint4(0u, 0u, 0u, 0u);
    if (n0 + r < nnodes) v = *(const uint4*)&Xb[(size_t)(n0 + r) * 128 + c8];
    *(uint4*)&Xs[r * 136 + c8] = v;
  }
#pragma unroll
  for (int it = 0; it < 8; ++it) {    // Ws: 128 x 128 bf16 (transposed W)
    int g = tid + it * 256;
    int r = g >> 4, c8 = (g & 15) * 8;
    uint4 v = *(const uint4*)&Wt[r * 128 + c8];
    *(uint4*)&Ws[r * 136 + c8] = v;
  }
  __syncthreads();

  f32x4 acc[8];
#pragma unroll
  for (int t = 0; t < 8; ++t) acc[t] = (f32x4){0.f, 0.f, 0.f, 0.f};
  const int arow = wid * 16 + lc;
#pragma unroll 1
  for (int ks = 0; ks < 4; ++ks) {
    const int k0 = ks * 32 + quad * 8;
    bf16x8 a = *(const bf16x8*)&Xs[arow * 136 + k0];
#pragma unroll
    for (int t = 0; t < 8; ++t) {
      bf16x8 b = *(const bf16x8*)&Ws[(t * 16 + lc) * 136 + k0];
      acc[t] = __builtin_amdgcn_mfma_f32_16x16x32_bf16(a, b, acc[t], 0, 0, 0);
    }
  }

  // attention partials from C-fragments
  float av_s[8], av_d[8];
#pragma unroll
  for (int t = 0; t < 8; ++t) { av_s[t] = avs[t * 16 + lc]; av_d[t] = avd[t * 16 + lc]; }
#pragma unroll
  for (int r = 0; r < 4; ++r) {
    float s0 = 0.f, s1 = 0.f, d0 = 0.f, d1 = 0.f;
#pragma unroll
    for (int t = 0; t < 4; ++t) { s0 += acc[t][r] * av_s[t]; d0 += acc[t][r] * av_d[t]; }
#pragma unroll
    for (int t = 4; t < 8; ++t) { s1 += acc[t][r] * av_s[t]; d1 += acc[t][r] * av_d[t]; }
    int row = wid * 16 + quad * 4 + r;
    atomicAdd(&es_s[0][row], s0); atomicAdd(&es_s[1][row], s1);
    atomicAdd(&ed_s[0][row], d0); atomicAdd(&ed_s[1][row], d1);
  }
  __syncthreads();              // all LDS reads done -> reuse Ws for output staging
  u16* hout = Ws;               // 64 rows x stride 136
#pragma unroll
  for (int t = 0; t < 8; ++t)
#pragma unroll
    for (int r = 0; r < 4; ++r)
      hout[(wid * 16 + quad * 4 + r) * 136 + t * 16 + lc] = f2bf(acc[t][r]);
  __syncthreads();
#pragma unroll
  for (int it = 0; it < 4; ++it) {   // coalesced bf16 writeback
    int g = tid + it * 256;
    int r = g >> 4, c8 = (g & 15) * 8;
    if (n0 + r < nnodes)
      *(uint4*)&hfeat[(size_t)(n0 + r) * 128 + c8] = *(const uint4*)&hout[r * 136 + c8];
  }
  if (tid < 64) {
    int n = n0 + tid;
    if (n < nnodes) {
      es[n * 2 + 0] = es_s[0][tid]; es[n * 2 + 1] = es_s[1][tid];
      ed[n * 2 + 0] = ed_s[0][tid]; ed[n * 2 + 1] = ed_s[1][tid];
    }
  }
}

// ---------------- per-edge softmax weights (both heads) ----------------
__global__ __launch_bounds__(256) void edge_w_kernel(
    const float* __restrict__ es, const float* __restrict__ ed,
    const int* __restrict__ csr_src, const int* __restrict__ csr_dst,
    float2* __restrict__ wbuf)
{
  int i = blockIdx.x * 256 + threadIdx.x;
  if (i >= ET) return;
  int s = csr_src[i], d = csr_dst[i];
  float2 esv = ((const float2*)es)[s];
  float2 edv = ((const float2*)ed)[d];
  float e0 = esv.x + edv.x, e1 = esv.y + edv.y;
  e0 = (e0 > 0.f) ? e0 : 0.2f * e0;
  e1 = (e1 > 0.f) ? e1 : 0.2f * e1;
  wbuf[i] = make_float2(__expf(e0), __expf(e1));
}

// ---------------- aggregation: one wave per node; bf16 in, bf16 out ----------------
__global__ __launch_bounds__(256) void aggregate_kernel(
    const uint32* __restrict__ hfeat, const float2* __restrict__ wbuf,
    const int* __restrict__ rowptr, const int* __restrict__ csr_src,
    const float* __restrict__ bias, u16* __restrict__ out, int nnodes)
{
  int n = (blockIdx.x * blockDim.x + threadIdx.x) >> 6;
  int lane = threadIdx.x & 63;
  if (n >= nnodes) return;
  int beg = rowptr[n], end = rowptr[n + 1];
  const bool hi = lane >= 32;
  float accE = 0.f, accO = 0.f, den = 0.f;

  int idxA[4]; float wA[4];
  int i = beg;
#pragma unroll
  for (int t = 0; t < 4; ++t) {
    int j = i + t;
    int jj = (j < end) ? j : beg;
    idxA[t] = csr_src[jj];
    float2 ww = wbuf[jj];
    float w = hi ? ww.y : ww.x;
    wA[t] = (j < end) ? w : 0.f;
  }
  i += 4;
  for (;;) {
    bool more = (i < end);
    int idxB[4]; float wB[4];
    if (more) {
#pragma unroll
      for (int t = 0; t < 4; ++t) {
        int j = i + t;
        int jj = (j < end) ? j : beg;
        idxB[t] = csr_src[jj];
        float2 ww = wbuf[jj];
        float w = hi ? ww.y : ww.x;
        wB[t] = (j < end) ? w : 0.f;
      }
    }
    uint32 hv[4];
#pragma unroll
    for (int t = 0; t < 4; ++t) hv[t] = hfeat[(size_t)idxA[t] * 64 + lane];
#pragma unroll
    for (int t = 0; t < 4; ++t) {
      accE = fmaf(wA[t], bflo(hv[t]), accE);
      accO = fmaf(wA[t], bfhi(hv[t]), accO);
      den += wA[t];
    }
    if (!more) break;
#pragma unroll
    for (int t = 0; t < 4; ++t) { idxA[t] = idxB[t]; wA[t] = wB[t]; }
    i += 4;
  }
  float inv = 1.f / den;
  int m = lane & 31;
  int off = hi ? 64 : 0;
  float2 bb = *(const float2*)&bias[off + 2 * m];
  float v0 = accE * inv + bb.x;
  float v1 = accO * inv + bb.y;
  v0 = (v0 > 0.f) ? v0 : (__expf(v0) - 1.f);  // ELU
  v1 = (v1 > 0.f) ? v1 : (__expf(v1) - 1.f);
  uint32 pk = ((uint32)f2bf(v1) << 16) | (uint32)f2bf(v0);
  ((uint32*)out)[(size_t)n * 64 + (hi ? 32 : 0) + m] = pk;
}

// ---------------- final linear (256->40) + log_softmax (bf16 inputs) ----------------
__global__ __launch_bounds__(256) void final_kernel(
    const u16* __restrict__ h1b, const u16* __restrict__ h2b,
    const float* __restrict__ lw, const float* __restrict__ lb,
    float* __restrict__ out, int nnodes)
{
  __shared__ __align__(16) float Hs[64][33];
  __shared__ __align__(16) float Ws2[32 * 40];
  const int tid = threadIdx.x;
  const int m = tid >> 2, q = tid & 3;
  const int n0 = blockIdx.x * 64;

  float bj[10];
#pragma unroll
  for (int j = 0; j < 10; ++j) bj[j] = lb[q * 10 + j];

  float acc[10];
#pragma unroll
  for (int j = 0; j < 10; ++j) acc[j] = 0.f;

  for (int kc = 0; kc < 256; kc += 32) {
    __syncthreads();
    {
      int nd = tid >> 2, g = tid & 3;   // 64 nodes x 4 groups of 8 bf16
      int n = n0 + nd;
      uint4 v = make_uint4(0u, 0u, 0u, 0u);
      if (n < nnodes) {
        const u16* src = (kc < 128) ? &h1b[(size_t)n * 128 + kc + g * 8]
                                    : &h2b[(size_t)n * 128 + (kc - 128) + g * 8];
        v = *(const uint4*)src;
      }
      float* hp = &Hs[nd][g * 8];
      hp[0] = bflo(v.x); hp[1] = bfhi(v.x); hp[2] = bflo(v.y); hp[3] = bfhi(v.y);
      hp[4] = bflo(v.z); hp[5] = bfhi(v.z); hp[6] = bflo(v.w); hp[7] = bfhi(v.w);
    }
    {
      float4 v = *(const float4*)&lw[kc * 40 + tid * 4];
      *(float4*)&Ws2[tid * 4] = v;
      if (tid < 64) {
        float4 v2 = *(const float4*)&lw[kc * 40 + (256 + tid) * 4];
        *(float4*)&Ws2[(256 + tid) * 4] = v2;
      }
    }
    __syncthreads();
#pragma unroll
    for (int k = 0; k < 32; ++k) {
      float a = Hs[m][k];
      const float* wr = &Ws2[k * 40 + q * 10];
#pragma unroll
      for (int j = 0; j < 10; ++j) acc[j] = fmaf(a, wr[j], acc[j]);
    }
  }

  float mx = -INFINITY;
#pragma unroll
  for (int j = 0; j < 10; ++j) { acc[j] += bj[j]; mx = fmaxf(mx, acc[j]); }
  mx = fmaxf(mx, __shfl_xor(mx, 1));
  mx = fmaxf(mx, __shfl_xor(mx, 2));
  float s = 0.f;
#pragma unroll
  for (int j = 0; j < 10; ++j) s += __expf(acc[j] - mx);
  s += __shfl_xor(s, 1);
  s += __shfl_xor(s, 2);
  float lg = mx + __logf(s);
  int n = n0 + m;
  if (n < nnodes) {
#pragma unroll
    for (int j = 0; j < 10; ++j) out[(size_t)n * 40 + q * 10 + j] = acc[j] - lg;
  }
}

// ---------------- launch ----------------

extern "C" void kernel_launch(void* const* d_in, const int* in_sizes, int n_in,
                              void* d_out, int out_size, void* d_ws, size_t ws_size,
                              hipStream_t stream) {
  const float* x   = (const float*)d_in[0];
  const int*   ei  = (const int*)d_in[1];
  const float* W0  = (const float*)d_in[2];
  const float* as0 = (const float*)d_in[3];
  const float* ad0 = (const float*)d_in[4];
  const float* b0  = (const float*)d_in[5];
  const float* W1  = (const float*)d_in[6];
  const float* as1 = (const float*)d_in[7];
  const float* ad1 = (const float*)d_in[8];
  const float* b1  = (const float*)d_in[9];
  const float* lw  = (const float*)d_in[10];
  const float* lb  = (const float*)d_in[11];
  float* out = (float*)d_out;

  char* p = (char*)d_ws;
  auto carve = [&](size_t bytes) { char* r = p; p += (bytes + 255) & ~(size_t)255; return r; };
  u16* xb     = (u16*)carve((size_t)NN * 128 * 2);
  u16* w0t    = (u16*)carve(128 * 128 * 2);
  u16* w1t    = (u16*)carve(128 * 128 * 2);
  u16* hfeat  = (u16*)carve((size_t)NN * 128 * 2);
  u16* h1b    = (u16*)carve((size_t)NN * 128 * 2);
  u16* h2b    = (u16*)carve((size_t)NN * 128 * 2);
  float* es   = (float*)carve((size_t)NN * 2 * 4);
  float* ed   = (float*)carve((size_t)NN * 2 * 4);
  int* rowptr = (int*)carve((size_t)(NN + 1) * 4);
  int* cnt    = (int*)carve((size_t)NN * 4);
  int* csr    = (int*)carve((size_t)ET * 4);
  int* csrd   = (int*)carve((size_t)ET * 4);
  float2* wbuf = (float2*)carve((size_t)ET * 8);
  int* bsum   = (int*)carve((size_t)NB * 4);
  int* boff   = (int*)carve((size_t)NB * 4);

  // prep (bf16 conversions + W transposes)
  prep_kernel<<<NBX + 2, 256, 0, stream>>>(x, W0, W1, xb, w0t, w1t);

  // CSR build (reused by both layers)
  zero_int_kernel<<<(NN + 1023) / 1024, 1024, 0, stream>>>(cnt, NN);
  count_kernel<<<(ET + 255) / 256, 256, 0, stream>>>(ei, cnt);
  scan_l1_kernel<<<NB, 256, 0, stream>>>(cnt, rowptr, bsum);
  scan_l2_kernel<<<1, 256, 0, stream>>>(bsum, boff, rowptr);
  scan_add_kernel<<<NB, 256, 0, stream>>>(rowptr, boff);
  zero_int_kernel<<<(NN + 1023) / 1024, 1024, 0, stream>>>(cnt, NN);
  scatter_kernel<<<(ET + 255) / 256, 256, 0, stream>>>(ei, rowptr, cnt, csr, csrd);

  // layer 1
  gemm_att_kernel<<<(NN + 63) / 64, 256, 0, stream>>>(xb, w0t, as0, ad0, hfeat, es, ed, NN);
  edge_w_kernel<<<(ET + 255) / 256, 256, 0, stream>>>(es, ed, csr, csrd, wbuf);
  aggregate_kernel<<<(NN * 64 + 255) / 256, 256, 0, stream>>>((const uint32*)hfeat, wbuf, rowptr, csr, b0, h1b, NN);
  // layer 2
  gemm_att_kernel<<<(NN + 63) / 64, 256, 0, stream>>>(h1b, w1t, as1, ad1, hfeat, es, ed, NN);
  edge_w_kernel<<<(ET + 255) / 256, 256, 0, stream>>>(es, ed, csr, csrd, wbuf);
  aggregate_kernel<<<(NN * 64 + 255) / 256, 256, 0, stream>>>((const uint32*)hfeat, wbuf, rowptr, csr, b1, h2b, NN);
  // head
  final_kernel<<<(NN + 63) / 64, 256, 0, stream>>>(h1b, h2b, lw, lb, out, NN);
}

// Round 9
// 409.773 us; speedup vs baseline: 8.8144x; 1.0647x over previous
//
#include <hip/hip_runtime.h>
#include <math.h>

#define NN 50000
#define E0 800000
#define ET 850000
#define NB 196   // ceil(NN/256) scan blocks
#define NBX 200  // prep: x-conversion blocks (+2 for W transposes)

typedef unsigned int uint32;
typedef unsigned short u16;
typedef __attribute__((ext_vector_type(8))) short bf16x8;  // 8 bf16 = 4 VGPRs
typedef __attribute__((ext_vector_type(4))) float f32x4;

__device__ __forceinline__ u16 f2bf(float f) {
  uint32 u = __float_as_uint(f);
  return (u16)((u + 0x7FFFu + ((u >> 16) & 1u)) >> 16);  // RNE
}
__device__ __forceinline__ float bflo(uint32 u) { return __uint_as_float(u << 16); }
__device__ __forceinline__ float bfhi(uint32 u) { return __uint_as_float(u & 0xFFFF0000u); }

// ---------------- prep: x -> bf16; W0,W1 -> bf16 transposed [n][k] ----------------
__global__ __launch_bounds__(256) void prep_kernel(
    const float* __restrict__ x, const float* __restrict__ W0, const float* __restrict__ W1,
    u16* __restrict__ xb, u16* __restrict__ w0t, u16* __restrict__ w1t)
{
  int b = blockIdx.x;
  if (b < NBX) {
    const float4* x4 = (const float4*)x;
    ushort4* xb4 = (ushort4*)xb;
    const int total = NN * 128 / 4;
    for (int i = b * 256 + threadIdx.x; i < total; i += NBX * 256) {
      float4 v = x4[i];
      ushort4 u;
      u.x = f2bf(v.x); u.y = f2bf(v.y); u.z = f2bf(v.z); u.w = f2bf(v.w);
      xb4[i] = u;
    }
  } else {
    const float* W = (b == NBX) ? W0 : W1;
    u16* Wt = (b == NBX) ? w0t : w1t;
    __shared__ float tile[32][129];
    const int tid = threadIdx.x;
    for (int k0 = 0; k0 < 128; k0 += 32) {
      __syncthreads();
#pragma unroll
      for (int it = 0; it < 4; ++it) {  // 32 k-rows x 128 n, coalesced
        int q = tid + it * 256;
        int kk = q >> 5, n4 = (q & 31) * 4;
        float4 v = *(const float4*)&W[(k0 + kk) * 128 + n4];
        tile[kk][n4 + 0] = v.x; tile[kk][n4 + 1] = v.y;
        tile[kk][n4 + 2] = v.z; tile[kk][n4 + 3] = v.w;
      }
      __syncthreads();
      int n = tid >> 1, h = (tid & 1) * 16;
      __align__(16) u16 tmp[16];
#pragma unroll
      for (int j = 0; j < 16; ++j) tmp[j] = f2bf(tile[h + j][n]);
      *(uint4*)&Wt[n * 128 + k0 + h] = *(uint4*)&tmp[0];
      *(uint4*)&Wt[n * 128 + k0 + h + 8] = *(uint4*)&tmp[8];
    }
  }
}

// ---------------- CSR build ----------------

__global__ void zero_int_kernel(int* __restrict__ p, int n) {
  int i = blockIdx.x * blockDim.x + threadIdx.x;
  if (i < n) p[i] = 0;
}

__global__ void count_kernel(const int* __restrict__ ei, int* __restrict__ cnt) {
  int e = blockIdx.x * blockDim.x + threadIdx.x;
  if (e >= ET) return;
  int dst = (e < E0) ? ei[E0 + e] : (e - E0);
  atomicAdd(&cnt[dst], 1);
}

__global__ __launch_bounds__(256) void scan_l1_kernel(const int* __restrict__ cnt,
                                                      int* __restrict__ rowptr,
                                                      int* __restrict__ bsum) {
  __shared__ int s[256];
  int i = blockIdx.x * 256 + threadIdx.x;
  int v = (i < NN) ? cnt[i] : 0;
  int val = v;
  s[threadIdx.x] = val;
  __syncthreads();
#pragma unroll
  for (int off = 1; off < 256; off <<= 1) {
    int t = (threadIdx.x >= (unsigned)off) ? s[threadIdx.x - off] : 0;
    __syncthreads();
    val += t;
    s[threadIdx.x] = val;
    __syncthreads();
  }
  if (i < NN) rowptr[i] = val - v;
  if (threadIdx.x == 255) bsum[blockIdx.x] = val;
}

__global__ __launch_bounds__(256) void scan_l2_kernel(const int* __restrict__ bsum,
                                                      int* __restrict__ boff,
                                                      int* __restrict__ rowptr) {
  __shared__ int s[256];
  int i = threadIdx.x;
  int v = (i < NB) ? bsum[i] : 0;
  int val = v;
  s[i] = val;
  __syncthreads();
#pragma unroll
  for (int off = 1; off < 256; off <<= 1) {
    int t = (i >= (unsigned)off) ? s[i - off] : 0;
    __syncthreads();
    val += t;
    s[i] = val;
    __syncthreads();
  }
  if (i < NB) boff[i] = val - v;
  if (i == NB - 1) rowptr[NN] = val;
}

__global__ __launch_bounds__(256) void scan_add_kernel(int* __restrict__ rowptr,
                                                       const int* __restrict__ boff) {
  int i = blockIdx.x * 256 + threadIdx.x;
  if (i < NN) rowptr[i] += boff[blockIdx.x];
}

__global__ void scatter_kernel(const int* __restrict__ ei, const int* __restrict__ rowptr,
                               int* __restrict__ cursor, int* __restrict__ csr_src,
                               int* __restrict__ csr_dst) {
  int e = blockIdx.x * blockDim.x + threadIdx.x;
  if (e >= ET) return;
  int src, dst;
  if (e < E0) { src = ei[e]; dst = ei[E0 + e]; }
  else        { src = e - E0; dst = src; }
  int pos = rowptr[dst] + atomicAdd(&cursor[dst], 1);
  csr_src[pos] = src;
  csr_dst[pos] = dst;
}

// ---------------- MFMA GEMM (Xb @ W) + attention logits ----------------
__global__ __launch_bounds__(256) void gemm_att_kernel(
    const u16* __restrict__ Xb, const u16* __restrict__ Wt,
    const float* __restrict__ avs, const float* __restrict__ avd,
    u16* __restrict__ hfeat, float* __restrict__ es, float* __restrict__ ed,
    int nnodes)
{
  __shared__ u16 Xs[64 * 136];    // 17.0 KB, padded stride 136
  __shared__ u16 Ws[128 * 136];   // 34.0 KB (reused as bf16 out-staging)
  __shared__ float es_s[2][64];
  __shared__ float ed_s[2][64];
  const int tid = threadIdx.x;
  const int wid = tid >> 6, lane = tid & 63;
  const int quad = lane >> 4, lc = lane & 15;
  const int n0 = blockIdx.x * 64;
  if (tid < 128) { es_s[tid >> 6][tid & 63] = 0.f; ed_s[tid >> 6][tid & 63] = 0.f; }

#pragma unroll
  for (int it = 0; it < 4; ++it) {    // Xs: 64 x 128 bf16
    int g = tid + it * 256;
    int r = g >> 4, c8 = (g & 15) * 8;
    uint4 v = make_uint4(0u, 0u, 0u, 0u);
    if (n0 + r < nnodes) v = *(const uint4*)&Xb[(size_t)(n0 + r) * 128 + c8];
    *(uint4*)&Xs[r * 136 + c8] = v;
  }
#pragma unroll
  for (int it = 0; it < 8; ++it) {    // Ws: 128 x 128 bf16 (transposed W)
    int g = tid + it * 256;
    int r = g >> 4, c8 = (g & 15) * 8;
    uint4 v = *(const uint4*)&Wt[r * 128 + c8];
    *(uint4*)&Ws[r * 136 + c8] = v;
  }
  __syncthreads();

  f32x4 acc[8];
#pragma unroll
  for (int t = 0; t < 8; ++t) acc[t] = (f32x4){0.f, 0.f, 0.f, 0.f};
  const int arow = wid * 16 + lc;
#pragma unroll 1
  for (int ks = 0; ks < 4; ++ks) {
    const int k0 = ks * 32 + quad * 8;
    bf16x8 a = *(const bf16x8*)&Xs[arow * 136 + k0];
#pragma unroll
    for (int t = 0; t < 8; ++t) {
      bf16x8 b = *(const bf16x8*)&Ws[(t * 16 + lc) * 136 + k0];
      acc[t] = __builtin_amdgcn_mfma_f32_16x16x32_bf16(a, b, acc[t], 0, 0, 0);
    }
  }

  // attention partials from C-fragments
  float av_s[8], av_d[8];
#pragma unroll
  for (int t = 0; t < 8; ++t) { av_s[t] = avs[t * 16 + lc]; av_d[t] = avd[t * 16 + lc]; }
#pragma unroll
  for (int r = 0; r < 4; ++r) {
    float s0 = 0.f, s1 = 0.f, d0 = 0.f, d1 = 0.f;
#pragma unroll
    for (int t = 0; t < 4; ++t) { s0 += acc[t][r] * av_s[t]; d0 += acc[t][r] * av_d[t]; }
#pragma unroll
    for (int t = 4; t < 8; ++t) { s1 += acc[t][r] * av_s[t]; d1 += acc[t][r] * av_d[t]; }
    int row = wid * 16 + quad * 4 + r;
    atomicAdd(&es_s[0][row], s0); atomicAdd(&es_s[1][row], s1);
    atomicAdd(&ed_s[0][row], d0); atomicAdd(&ed_s[1][row], d1);
  }
  __syncthreads();              // all LDS reads done -> reuse Ws for output staging
  u16* hout = Ws;               // 64 rows x stride 136
#pragma unroll
  for (int t = 0; t < 8; ++t)
#pragma unroll
    for (int r = 0; r < 4; ++r)
      hout[(wid * 16 + quad * 4 + r) * 136 + t * 16 + lc] = f2bf(acc[t][r]);
  __syncthreads();
#pragma unroll
  for (int it = 0; it < 4; ++it) {   // coalesced bf16 writeback
    int g = tid + it * 256;
    int r = g >> 4, c8 = (g & 15) * 8;
    if (n0 + r < nnodes)
      *(uint4*)&hfeat[(size_t)(n0 + r) * 128 + c8] = *(const uint4*)&hout[r * 136 + c8];
  }
  if (tid < 64) {
    int n = n0 + tid;
    if (n < nnodes) {
      es[n * 2 + 0] = es_s[0][tid]; es[n * 2 + 1] = es_s[1][tid];
      ed[n * 2 + 0] = ed_s[0][tid]; ed[n * 2 + 1] = ed_s[1][tid];
    }
  }
}

// ---------------- per-edge softmax weights (both heads) ----------------
__global__ __launch_bounds__(256) void edge_w_kernel(
    const float* __restrict__ es, const float* __restrict__ ed,
    const int* __restrict__ csr_src, const int* __restrict__ csr_dst,
    float2* __restrict__ wbuf)
{
  int i = blockIdx.x * 256 + threadIdx.x;
  if (i >= ET) return;
  int s = csr_src[i], d = csr_dst[i];
  float2 esv = ((const float2*)es)[s];
  float2 edv = ((const float2*)ed)[d];
  float e0 = esv.x + edv.x, e1 = esv.y + edv.y;
  e0 = (e0 > 0.f) ? e0 : 0.2f * e0;
  e1 = (e1 > 0.f) ? e1 : 0.2f * e1;
  wbuf[i] = make_float2(__expf(e0), __expf(e1));
}

// ---------------- aggregation: one wave per node, 4 edges/iter ----------------
// Quarter-wave (16 lanes) covers one edge's full 256 B row as uint4 (8 bf16
// features per lane). eg = lane>>4 picks the edge within the chunk of 4;
// butterfly shfl_xor(16,32) combines the 4 edge-groups at the end.
__global__ __launch_bounds__(256) void aggregate_kernel(
    const uint4* __restrict__ hfeat4, const float2* __restrict__ wbuf,
    const int* __restrict__ rowptr, const int* __restrict__ csr_src,
    const float* __restrict__ bias, u16* __restrict__ out, int nnodes)
{
  int n = (blockIdx.x * blockDim.x + threadIdx.x) >> 6;
  int lane = threadIdx.x & 63;
  if (n >= nnodes) return;
  const int eg = lane >> 4;       // edge group 0..3
  const int fl = lane & 15;       // feature lane: bf16 features fl*8..fl*8+7
  const bool hd1 = fl >= 8;       // head of this lane's features
  const int beg = rowptr[n], end = rowptr[n + 1];
  const int nch = (end - beg + 3) >> 2;
  const int j0 = beg + eg;

  float acc[8];
#pragma unroll
  for (int t = 0; t < 8; ++t) acc[t] = 0.f;
  float den = 0.f;

  int idxA; float wA;
  {
    int j = j0;
    int jj = (j < end) ? j : beg;
    idxA = csr_src[jj];
    float2 ww = wbuf[jj];
    wA = (j < end) ? (hd1 ? ww.y : ww.x) : 0.f;
  }
  for (int c = 0;;) {
    uint4 hv = hfeat4[(size_t)idxA * 16 + fl];
    bool more = (c + 1 < nch);
    int idxB; float wB;
    if (more) {
      int j = j0 + (c + 1) * 4;
      int jj = (j < end) ? j : beg;
      idxB = csr_src[jj];
      float2 ww = wbuf[jj];
      wB = (j < end) ? (hd1 ? ww.y : ww.x) : 0.f;
    }
    acc[0] = fmaf(wA, bflo(hv.x), acc[0]);
    acc[1] = fmaf(wA, bfhi(hv.x), acc[1]);
    acc[2] = fmaf(wA, bflo(hv.y), acc[2]);
    acc[3] = fmaf(wA, bfhi(hv.y), acc[3]);
    acc[4] = fmaf(wA, bflo(hv.z), acc[4]);
    acc[5] = fmaf(wA, bfhi(hv.z), acc[5]);
    acc[6] = fmaf(wA, bflo(hv.w), acc[6]);
    acc[7] = fmaf(wA, bfhi(hv.w), acc[7]);
    den += wA;
    if (!more) break;
    idxA = idxB; wA = wB;
    ++c;
  }

  // combine the 4 edge-groups (lanes fl, fl+16, fl+32, fl+48)
#pragma unroll
  for (int t = 0; t < 8; ++t) {
    acc[t] += __shfl_xor(acc[t], 16);
    acc[t] += __shfl_xor(acc[t], 32);
  }
  den += __shfl_xor(den, 16);
  den += __shfl_xor(den, 32);

  if (eg == 0) {
    float inv = 1.f / den;
    float4 b0 = *(const float4*)&bias[fl * 8];
    float4 b1 = *(const float4*)&bias[fl * 8 + 4];
    float bv[8] = {b0.x, b0.y, b0.z, b0.w, b1.x, b1.y, b1.z, b1.w};
    u16 pk[8];
#pragma unroll
    for (int t = 0; t < 8; ++t) {
      float v = acc[t] * inv + bv[t];
      v = (v > 0.f) ? v : (__expf(v) - 1.f);  // ELU
      pk[t] = f2bf(v);
    }
    uint4 o;
    o.x = (uint32)pk[0] | ((uint32)pk[1] << 16);
    o.y = (uint32)pk[2] | ((uint32)pk[3] << 16);
    o.z = (uint32)pk[4] | ((uint32)pk[5] << 16);
    o.w = (uint32)pk[6] | ((uint32)pk[7] << 16);
    ((uint4*)out)[(size_t)n * 16 + fl] = o;
  }
}

// ---------------- final linear (256->40) + log_softmax (bf16 inputs) ----------------
__global__ __launch_bounds__(256) void final_kernel(
    const u16* __restrict__ h1b, const u16* __restrict__ h2b,
    const float* __restrict__ lw, const float* __restrict__ lb,
    float* __restrict__ out, int nnodes)
{
  __shared__ __align__(16) float Hs[64][33];
  __shared__ __align__(16) float Ws2[32 * 40];
  const int tid = threadIdx.x;
  const int m = tid >> 2, q = tid & 3;
  const int n0 = blockIdx.x * 64;

  float bj[10];
#pragma unroll
  for (int j = 0; j < 10; ++j) bj[j] = lb[q * 10 + j];

  float acc[10];
#pragma unroll
  for (int j = 0; j < 10; ++j) acc[j] = 0.f;

  for (int kc = 0; kc < 256; kc += 32) {
    __syncthreads();
    {
      int nd = tid >> 2, g = tid & 3;   // 64 nodes x 4 groups of 8 bf16
      int n = n0 + nd;
      uint4 v = make_uint4(0u, 0u, 0u, 0u);
      if (n < nnodes) {
        const u16* src = (kc < 128) ? &h1b[(size_t)n * 128 + kc + g * 8]
                                    : &h2b[(size_t)n * 128 + (kc - 128) + g * 8];
        v = *(const uint4*)src;
      }
      float* hp = &Hs[nd][g * 8];
      hp[0] = bflo(v.x); hp[1] = bfhi(v.x); hp[2] = bflo(v.y); hp[3] = bfhi(v.y);
      hp[4] = bflo(v.z); hp[5] = bfhi(v.z); hp[6] = bflo(v.w); hp[7] = bfhi(v.w);
    }
    {
      float4 v = *(const float4*)&lw[kc * 40 + tid * 4];
      *(float4*)&Ws2[tid * 4] = v;
      if (tid < 64) {
        float4 v2 = *(const float4*)&lw[kc * 40 + (256 + tid) * 4];
        *(float4*)&Ws2[(256 + tid) * 4] = v2;
      }
    }
    __syncthreads();
#pragma unroll
    for (int k = 0; k < 32; ++k) {
      float a = Hs[m][k];
      const float* wr = &Ws2[k * 40 + q * 10];
#pragma unroll
      for (int j = 0; j < 10; ++j) acc[j] = fmaf(a, wr[j], acc[j]);
    }
  }

  float mx = -INFINITY;
#pragma unroll
  for (int j = 0; j < 10; ++j) { acc[j] += bj[j]; mx = fmaxf(mx, acc[j]); }
  mx = fmaxf(mx, __shfl_xor(mx, 1));
  mx = fmaxf(mx, __shfl_xor(mx, 2));
  float s = 0.f;
#pragma unroll
  for (int j = 0; j < 10; ++j) s += __expf(acc[j] - mx);
  s += __shfl_xor(s, 1);
  s += __shfl_xor(s, 2);
  float lg = mx + __logf(s);
  int n = n0 + m;
  if (n < nnodes) {
#pragma unroll
    for (int j = 0; j < 10; ++j) out[(size_t)n * 40 + q * 10 + j] = acc[j] - lg;
  }
}

// ---------------- launch ----------------

extern "C" void kernel_launch(void* const* d_in, const int* in_sizes, int n_in,
                              void* d_out, int out_size, void* d_ws, size_t ws_size,
                              hipStream_t stream) {
  const float* x   = (const float*)d_in[0];
  const int*   ei  = (const int*)d_in[1];
  const float* W0  = (const float*)d_in[2];
  const float* as0 = (const float*)d_in[3];
  const float* ad0 = (const float*)d_in[4];
  const float* b0  = (const float*)d_in[5];
  const float* W1  = (const float*)d_in[6];
  const float* as1 = (const float*)d_in[7];
  const float* ad1 = (const float*)d_in[8];
  const float* b1  = (const float*)d_in[9];
  const float* lw  = (const float*)d_in[10];
  const float* lb  = (const float*)d_in[11];
  float* out = (float*)d_out;

  char* p = (char*)d_ws;
  auto carve = [&](size_t bytes) { char* r = p; p += (bytes + 255) & ~(size_t)255; return r; };
  u16* xb     = (u16*)carve((size_t)NN * 128 * 2);
  u16* w0t    = (u16*)carve(128 * 128 * 2);
  u16* w1t    = (u16*)carve(128 * 128 * 2);
  u16* hfeat  = (u16*)carve((size_t)NN * 128 * 2);
  u16* h1b    = (u16*)carve((size_t)NN * 128 * 2);
  u16* h2b    = (u16*)carve((size_t)NN * 128 * 2);
  float* es   = (float*)carve((size_t)NN * 2 * 4);
  float* ed   = (float*)carve((size_t)NN * 2 * 4);
  int* rowptr = (int*)carve((size_t)(NN + 1) * 4);
  int* cnt    = (int*)carve((size_t)NN * 4);
  int* csr    = (int*)carve((size_t)ET * 4);
  int* csrd   = (int*)carve((size_t)ET * 4);
  float2* wbuf = (float2*)carve((size_t)ET * 8);
  int* bsum   = (int*)carve((size_t)NB * 4);
  int* boff   = (int*)carve((size_t)NB * 4);

  // prep (bf16 conversions + W transposes)
  prep_kernel<<<NBX + 2, 256, 0, stream>>>(x, W0, W1, xb, w0t, w1t);

  // CSR build (reused by both layers)
  zero_int_kernel<<<(NN + 1023) / 1024, 1024, 0, stream>>>(cnt, NN);
  count_kernel<<<(ET + 255) / 256, 256, 0, stream>>>(ei, cnt);
  scan_l1_kernel<<<NB, 256, 0, stream>>>(cnt, rowptr, bsum);
  scan_l2_kernel<<<1, 256, 0, stream>>>(bsum, boff, rowptr);
  scan_add_kernel<<<NB, 256, 0, stream>>>(rowptr, boff);
  zero_int_kernel<<<(NN + 1023) / 1024, 1024, 0, stream>>>(cnt, NN);
  scatter_kernel<<<(ET + 255) / 256, 256, 0, stream>>>(ei, rowptr, cnt, csr, csrd);

  // layer 1
  gemm_att_kernel<<<(NN + 63) / 64, 256, 0, stream>>>(xb, w0t, as0, ad0, hfeat, es, ed, NN);
  edge_w_kernel<<<(ET + 255) / 256, 256, 0, stream>>>(es, ed, csr, csrd, wbuf);
  aggregate_kernel<<<(NN * 64 + 255) / 256, 256, 0, stream>>>((const uint4*)hfeat, wbuf, rowptr, csr, b0, h1b, NN);
  // layer 2
  gemm_att_kernel<<<(NN + 63) / 64, 256, 0, stream>>>(h1b, w1t, as1, ad1, hfeat, es, ed, NN);
  edge_w_kernel<<<(ET + 255) / 256, 256, 0, stream>>>(es, ed, csr, csrd, wbuf);
  aggregate_kernel<<<(NN * 64 + 255) / 256, 256, 0, stream>>>((const uint4*)hfeat, wbuf, rowptr, csr, b1, h2b, NN);
  // head
  final_kernel<<<(NN + 63) / 64, 256, 0, stream>>>(h1b, h2b, lw, lb, out, NN);
}

// Round 10
// 391.683 us; speedup vs baseline: 9.2215x; 1.0462x over previous
//
#include <hip/hip_runtime.h>
#include <math.h>

#define NN 50000
#define E0 800000
#define ET 850000
#define NB 196   // ceil(NN/256) scan blocks
#define NBX 200  // prep: x-conversion blocks (+2 for W transposes)

typedef unsigned int uint32;
typedef unsigned short u16;
typedef __attribute__((ext_vector_type(8))) short bf16x8;  // 8 bf16 = 4 VGPRs
typedef __attribute__((ext_vector_type(4))) float f32x4;

__device__ __forceinline__ u16 f2bf(float f) {
  uint32 u = __float_as_uint(f);
  return (u16)((u + 0x7FFFu + ((u >> 16) & 1u)) >> 16);  // RNE
}
__device__ __forceinline__ float bflo(uint32 u) { return __uint_as_float(u << 16); }
__device__ __forceinline__ float bfhi(uint32 u) { return __uint_as_float(u & 0xFFFF0000u); }

// ---------------- prep: x -> bf16; W0,W1 -> bf16 transposed [n][k] ----------------
__global__ __launch_bounds__(256) void prep_kernel(
    const float* __restrict__ x, const float* __restrict__ W0, const float* __restrict__ W1,
    u16* __restrict__ xb, u16* __restrict__ w0t, u16* __restrict__ w1t)
{
  int b = blockIdx.x;
  if (b < NBX) {
    const float4* x4 = (const float4*)x;
    ushort4* xb4 = (ushort4*)xb;
    const int total = NN * 128 / 4;
    for (int i = b * 256 + threadIdx.x; i < total; i += NBX * 256) {
      float4 v = x4[i];
      ushort4 u;
      u.x = f2bf(v.x); u.y = f2bf(v.y); u.z = f2bf(v.z); u.w = f2bf(v.w);
      xb4[i] = u;
    }
  } else {
    const float* W = (b == NBX) ? W0 : W1;
    u16* Wt = (b == NBX) ? w0t : w1t;
    __shared__ float tile[32][129];
    const int tid = threadIdx.x;
    for (int k0 = 0; k0 < 128; k0 += 32) {
      __syncthreads();
#pragma unroll
      for (int it = 0; it < 4; ++it) {  // 32 k-rows x 128 n, coalesced
        int q = tid + it * 256;
        int kk = q >> 5, n4 = (q & 31) * 4;
        float4 v = *(const float4*)&W[(k0 + kk) * 128 + n4];
        tile[kk][n4 + 0] = v.x; tile[kk][n4 + 1] = v.y;
        tile[kk][n4 + 2] = v.z; tile[kk][n4 + 3] = v.w;
      }
      __syncthreads();
      int n = tid >> 1, h = (tid & 1) * 16;
      __align__(16) u16 tmp[16];
#pragma unroll
      for (int j = 0; j < 16; ++j) tmp[j] = f2bf(tile[h + j][n]);
      *(uint4*)&Wt[n * 128 + k0 + h] = *(uint4*)&tmp[0];
      *(uint4*)&Wt[n * 128 + k0 + h + 8] = *(uint4*)&tmp[8];
    }
  }
}

// ---------------- CSR build ----------------

__global__ void zero_int_kernel(int* __restrict__ p, int n) {
  int i = blockIdx.x * blockDim.x + threadIdx.x;
  if (i < n) p[i] = 0;
}

__global__ void count_kernel(const int* __restrict__ ei, int* __restrict__ cnt) {
  int e = blockIdx.x * blockDim.x + threadIdx.x;
  if (e >= ET) return;
  int dst = (e < E0) ? ei[E0 + e] : (e - E0);
  atomicAdd(&cnt[dst], 1);
}

__global__ __launch_bounds__(256) void scan_l1_kernel(const int* __restrict__ cnt,
                                                      int* __restrict__ rowptr,
                                                      int* __restrict__ bsum) {
  __shared__ int s[256];
  int i = blockIdx.x * 256 + threadIdx.x;
  int v = (i < NN) ? cnt[i] : 0;
  int val = v;
  s[threadIdx.x] = val;
  __syncthreads();
#pragma unroll
  for (int off = 1; off < 256; off <<= 1) {
    int t = (threadIdx.x >= (unsigned)off) ? s[threadIdx.x - off] : 0;
    __syncthreads();
    val += t;
    s[threadIdx.x] = val;
    __syncthreads();
  }
  if (i < NN) rowptr[i] = val - v;
  if (threadIdx.x == 255) bsum[blockIdx.x] = val;
}

__global__ __launch_bounds__(256) void scan_l2_kernel(const int* __restrict__ bsum,
                                                      int* __restrict__ boff,
                                                      int* __restrict__ rowptr) {
  __shared__ int s[256];
  int i = threadIdx.x;
  int v = (i < NB) ? bsum[i] : 0;
  int val = v;
  s[i] = val;
  __syncthreads();
#pragma unroll
  for (int off = 1; off < 256; off <<= 1) {
    int t = (i >= (unsigned)off) ? s[i - off] : 0;
    __syncthreads();
    val += t;
    s[i] = val;
    __syncthreads();
  }
  if (i < NB) boff[i] = val - v;
  if (i == NB - 1) rowptr[NN] = val;
}

__global__ __launch_bounds__(256) void scan_add_kernel(int* __restrict__ rowptr,
                                                       const int* __restrict__ boff) {
  int i = blockIdx.x * 256 + threadIdx.x;
  if (i < NN) rowptr[i] += boff[blockIdx.x];
}

// single 4B random store per edge (csr_dst removed; dst is implicit in aggregate)
__global__ void scatter_kernel(const int* __restrict__ ei, const int* __restrict__ rowptr,
                               int* __restrict__ cursor, int* __restrict__ csr_src) {
  int e = blockIdx.x * blockDim.x + threadIdx.x;
  if (e >= ET) return;
  int src, dst;
  if (e < E0) { src = ei[e]; dst = ei[E0 + e]; }
  else        { src = e - E0; dst = src; }
  int pos = rowptr[dst] + atomicAdd(&cursor[dst], 1);
  csr_src[pos] = src;
}

// ---------------- MFMA GEMM (Xb @ W) + attention logits ----------------
__global__ __launch_bounds__(256) void gemm_att_kernel(
    const u16* __restrict__ Xb, const u16* __restrict__ Wt,
    const float* __restrict__ avs, const float* __restrict__ avd,
    u16* __restrict__ hfeat, float* __restrict__ es, float* __restrict__ ed,
    int nnodes)
{
  __shared__ u16 Xs[64 * 136];    // 17.0 KB, padded stride 136
  __shared__ u16 Ws[128 * 136];   // 34.0 KB (reused as bf16 out-staging)
  __shared__ float es_s[2][64];
  __shared__ float ed_s[2][64];
  const int tid = threadIdx.x;
  const int wid = tid >> 6, lane = tid & 63;
  const int quad = lane >> 4, lc = lane & 15;
  const int n0 = blockIdx.x * 64;
  if (tid < 128) { es_s[tid >> 6][tid & 63] = 0.f; ed_s[tid >> 6][tid & 63] = 0.f; }

#pragma unroll
  for (int it = 0; it < 4; ++it) {    // Xs: 64 x 128 bf16
    int g = tid + it * 256;
    int r = g >> 4, c8 = (g & 15) * 8;
    uint4 v = make_uint4(0u, 0u, 0u, 0u);
    if (n0 + r < nnodes) v = *(const uint4*)&Xb[(size_t)(n0 + r) * 128 + c8];
    *(uint4*)&Xs[r * 136 + c8] = v;
  }
#pragma unroll
  for (int it = 0; it < 8; ++it) {    // Ws: 128 x 128 bf16 (transposed W)
    int g = tid + it * 256;
    int r = g >> 4, c8 = (g & 15) * 8;
    uint4 v = *(const uint4*)&Wt[r * 128 + c8];
    *(uint4*)&Ws[r * 136 + c8] = v;
  }
  __syncthreads();

  f32x4 acc[8];
#pragma unroll
  for (int t = 0; t < 8; ++t) acc[t] = (f32x4){0.f, 0.f, 0.f, 0.f};
  const int arow = wid * 16 + lc;
#pragma unroll 1
  for (int ks = 0; ks < 4; ++ks) {
    const int k0 = ks * 32 + quad * 8;
    bf16x8 a = *(const bf16x8*)&Xs[arow * 136 + k0];
#pragma unroll
    for (int t = 0; t < 8; ++t) {
      bf16x8 b = *(const bf16x8*)&Ws[(t * 16 + lc) * 136 + k0];
      acc[t] = __builtin_amdgcn_mfma_f32_16x16x32_bf16(a, b, acc[t], 0, 0, 0);
    }
  }

  // attention partials from C-fragments
  float av_s[8], av_d[8];
#pragma unroll
  for (int t = 0; t < 8; ++t) { av_s[t] = avs[t * 16 + lc]; av_d[t] = avd[t * 16 + lc]; }
#pragma unroll
  for (int r = 0; r < 4; ++r) {
    float s0 = 0.f, s1 = 0.f, d0 = 0.f, d1 = 0.f;
#pragma unroll
    for (int t = 0; t < 4; ++t) { s0 += acc[t][r] * av_s[t]; d0 += acc[t][r] * av_d[t]; }
#pragma unroll
    for (int t = 4; t < 8; ++t) { s1 += acc[t][r] * av_s[t]; d1 += acc[t][r] * av_d[t]; }
    int row = wid * 16 + quad * 4 + r;
    atomicAdd(&es_s[0][row], s0); atomicAdd(&es_s[1][row], s1);
    atomicAdd(&ed_s[0][row], d0); atomicAdd(&ed_s[1][row], d1);
  }
  __syncthreads();              // all LDS reads done -> reuse Ws for output staging
  u16* hout = Ws;               // 64 rows x stride 136
#pragma unroll
  for (int t = 0; t < 8; ++t)
#pragma unroll
    for (int r = 0; r < 4; ++r)
      hout[(wid * 16 + quad * 4 + r) * 136 + t * 16 + lc] = f2bf(acc[t][r]);
  __syncthreads();
#pragma unroll
  for (int it = 0; it < 4; ++it) {   // coalesced bf16 writeback
    int g = tid + it * 256;
    int r = g >> 4, c8 = (g & 15) * 8;
    if (n0 + r < nnodes)
      *(uint4*)&hfeat[(size_t)(n0 + r) * 128 + c8] = *(const uint4*)&hout[r * 136 + c8];
  }
  if (tid < 64) {
    int n = n0 + tid;
    if (n < nnodes) {
      es[n * 2 + 0] = es_s[0][tid]; es[n * 2 + 1] = es_s[1][tid];
      ed[n * 2 + 0] = ed_s[0][tid]; ed[n * 2 + 1] = ed_s[1][tid];
    }
  }
}

// ---------------- aggregation: one wave per node, 4 edges/iter, fused softmax ----------------
// Quarter-wave (16 lanes) covers one edge's 256 B bf16 row as uint4. Edge weight
// w = exp(leakyrelu(es[src]+ed[n])) computed inline (es is L2-resident, 400 KB).
__global__ __launch_bounds__(256) void aggregate_kernel(
    const uint4* __restrict__ hfeat4, const float* __restrict__ es, const float* __restrict__ ed,
    const int* __restrict__ rowptr, const int* __restrict__ csr_src,
    const float* __restrict__ bias, u16* __restrict__ out, int nnodes)
{
  int n = (blockIdx.x * blockDim.x + threadIdx.x) >> 6;
  int lane = threadIdx.x & 63;
  if (n >= nnodes) return;
  const int eg = lane >> 4;       // edge group 0..3
  const int fl = lane & 15;       // feature lane: bf16 features fl*8..fl*8+7
  const int hd = (fl >= 8) ? 1 : 0;
  const int beg = rowptr[n], end = rowptr[n + 1];
  const int nch = (end - beg + 3) >> 2;
  const int j0 = beg + eg;
  const float edn = ed[n * 2 + hd];

  float acc[8];
#pragma unroll
  for (int t = 0; t < 8; ++t) acc[t] = 0.f;
  float den = 0.f;

  int idxA; float wA;
  {
    int j = j0;
    int jj = (j < end) ? j : beg;
    idxA = csr_src[jj];
    float e = es[idxA * 2 + hd] + edn;
    e = (e > 0.f) ? e : 0.2f * e;
    wA = (j < end) ? __expf(e) : 0.f;
  }
  for (int c = 0;;) {
    uint4 hv = hfeat4[(size_t)idxA * 16 + fl];
    bool more = (c + 1 < nch);
    int idxB; float wB;
    if (more) {
      int j = j0 + (c + 1) * 4;
      int jj = (j < end) ? j : beg;
      idxB = csr_src[jj];
      float e = es[idxB * 2 + hd] + edn;
      e = (e > 0.f) ? e : 0.2f * e;
      wB = (j < end) ? __expf(e) : 0.f;
    }
    acc[0] = fmaf(wA, bflo(hv.x), acc[0]);
    acc[1] = fmaf(wA, bfhi(hv.x), acc[1]);
    acc[2] = fmaf(wA, bflo(hv.y), acc[2]);
    acc[3] = fmaf(wA, bfhi(hv.y), acc[3]);
    acc[4] = fmaf(wA, bflo(hv.z), acc[4]);
    acc[5] = fmaf(wA, bfhi(hv.z), acc[5]);
    acc[6] = fmaf(wA, bflo(hv.w), acc[6]);
    acc[7] = fmaf(wA, bfhi(hv.w), acc[7]);
    den += wA;
    if (!more) break;
    idxA = idxB; wA = wB;
    ++c;
  }

  // combine the 4 edge-groups (lanes fl, fl+16, fl+32, fl+48)
#pragma unroll
  for (int t = 0; t < 8; ++t) {
    acc[t] += __shfl_xor(acc[t], 16);
    acc[t] += __shfl_xor(acc[t], 32);
  }
  den += __shfl_xor(den, 16);
  den += __shfl_xor(den, 32);

  if (eg == 0) {
    float inv = 1.f / den;
    float4 b0 = *(const float4*)&bias[fl * 8];
    float4 b1 = *(const float4*)&bias[fl * 8 + 4];
    float bv[8] = {b0.x, b0.y, b0.z, b0.w, b1.x, b1.y, b1.z, b1.w};
    u16 pk[8];
#pragma unroll
    for (int t = 0; t < 8; ++t) {
      float v = acc[t] * inv + bv[t];
      v = (v > 0.f) ? v : (__expf(v) - 1.f);  // ELU
      pk[t] = f2bf(v);
    }
    uint4 o;
    o.x = (uint32)pk[0] | ((uint32)pk[1] << 16);
    o.y = (uint32)pk[2] | ((uint32)pk[3] << 16);
    o.z = (uint32)pk[4] | ((uint32)pk[5] << 16);
    o.w = (uint32)pk[6] | ((uint32)pk[7] << 16);
    ((uint4*)out)[(size_t)n * 16 + fl] = o;
  }
}

// ---------------- final linear (256->40) + log_softmax (bf16 inputs) ----------------
__global__ __launch_bounds__(256) void final_kernel(
    const u16* __restrict__ h1b, const u16* __restrict__ h2b,
    const float* __restrict__ lw, const float* __restrict__ lb,
    float* __restrict__ out, int nnodes)
{
  __shared__ __align__(16) float Hs[64][33];
  __shared__ __align__(16) float Ws2[32 * 40];
  const int tid = threadIdx.x;
  const int m = tid >> 2, q = tid & 3;
  const int n0 = blockIdx.x * 64;

  float bj[10];
#pragma unroll
  for (int j = 0; j < 10; ++j) bj[j] = lb[q * 10 + j];

  float acc[10];
#pragma unroll
  for (int j = 0; j < 10; ++j) acc[j] = 0.f;

  for (int kc = 0; kc < 256; kc += 32) {
    __syncthreads();
    {
      int nd = tid >> 2, g = tid & 3;   // 64 nodes x 4 groups of 8 bf16
      int n = n0 + nd;
      uint4 v = make_uint4(0u, 0u, 0u, 0u);
      if (n < nnodes) {
        const u16* src = (kc < 128) ? &h1b[(size_t)n * 128 + kc + g * 8]
                                    : &h2b[(size_t)n * 128 + (kc - 128) + g * 8];
        v = *(const uint4*)src;
      }
      float* hp = &Hs[nd][g * 8];
      hp[0] = bflo(v.x); hp[1] = bfhi(v.x); hp[2] = bflo(v.y); hp[3] = bfhi(v.y);
      hp[4] = bflo(v.z); hp[5] = bfhi(v.z); hp[6] = bflo(v.w); hp[7] = bfhi(v.w);
    }
    {
      float4 v = *(const float4*)&lw[kc * 40 + tid * 4];
      *(float4*)&Ws2[tid * 4] = v;
      if (tid < 64) {
        float4 v2 = *(const float4*)&lw[kc * 40 + (256 + tid) * 4];
        *(float4*)&Ws2[(256 + tid) * 4] = v2;
      }
    }
    __syncthreads();
#pragma unroll
    for (int k = 0; k < 32; ++k) {
      float a = Hs[m][k];
      const float* wr = &Ws2[k * 40 + q * 10];
#pragma unroll
      for (int j = 0; j < 10; ++j) acc[j] = fmaf(a, wr[j], acc[j]);
    }
  }

  float mx = -INFINITY;
#pragma unroll
  for (int j = 0; j < 10; ++j) { acc[j] += bj[j]; mx = fmaxf(mx, acc[j]); }
  mx = fmaxf(mx, __shfl_xor(mx, 1));
  mx = fmaxf(mx, __shfl_xor(mx, 2));
  float s = 0.f;
#pragma unroll
  for (int j = 0; j < 10; ++j) s += __expf(acc[j] - mx);
  s += __shfl_xor(s, 1);
  s += __shfl_xor(s, 2);
  float lg = mx + __logf(s);
  int n = n0 + m;
  if (n < nnodes) {
#pragma unroll
    for (int j = 0; j < 10; ++j) out[(size_t)n * 40 + q * 10 + j] = acc[j] - lg;
  }
}

// ---------------- launch ----------------

extern "C" void kernel_launch(void* const* d_in, const int* in_sizes, int n_in,
                              void* d_out, int out_size, void* d_ws, size_t ws_size,
                              hipStream_t stream) {
  const float* x   = (const float*)d_in[0];
  const int*   ei  = (const int*)d_in[1];
  const float* W0  = (const float*)d_in[2];
  const float* as0 = (const float*)d_in[3];
  const float* ad0 = (const float*)d_in[4];
  const float* b0  = (const float*)d_in[5];
  const float* W1  = (const float*)d_in[6];
  const float* as1 = (const float*)d_in[7];
  const float* ad1 = (const float*)d_in[8];
  const float* b1  = (const float*)d_in[9];
  const float* lw  = (const float*)d_in[10];
  const float* lb  = (const float*)d_in[11];
  float* out = (float*)d_out;

  char* p = (char*)d_ws;
  auto carve = [&](size_t bytes) { char* r = p; p += (bytes + 255) & ~(size_t)255; return r; };
  u16* xb     = (u16*)carve((size_t)NN * 128 * 2);
  u16* w0t    = (u16*)carve(128 * 128 * 2);
  u16* w1t    = (u16*)carve(128 * 128 * 2);
  u16* hfeat  = (u16*)carve((size_t)NN * 128 * 2);
  u16* h1b    = (u16*)carve((size_t)NN * 128 * 2);
  u16* h2b    = (u16*)carve((size_t)NN * 128 * 2);
  float* es   = (float*)carve((size_t)NN * 2 * 4);
  float* ed   = (float*)carve((size_t)NN * 2 * 4);
  int* rowptr = (int*)carve((size_t)(NN + 1) * 4);
  int* cnt    = (int*)carve((size_t)NN * 4);
  int* csr    = (int*)carve((size_t)ET * 4);
  int* bsum   = (int*)carve((size_t)NB * 4);
  int* boff   = (int*)carve((size_t)NB * 4);

  // prep (bf16 conversions + W transposes)
  prep_kernel<<<NBX + 2, 256, 0, stream>>>(x, W0, W1, xb, w0t, w1t);

  // CSR build (reused by both layers)
  zero_int_kernel<<<(NN + 1023) / 1024, 1024, 0, stream>>>(cnt, NN);
  count_kernel<<<(ET + 255) / 256, 256, 0, stream>>>(ei, cnt);
  scan_l1_kernel<<<NB, 256, 0, stream>>>(cnt, rowptr, bsum);
  scan_l2_kernel<<<1, 256, 0, stream>>>(bsum, boff, rowptr);
  scan_add_kernel<<<NB, 256, 0, stream>>>(rowptr, boff);
  zero_int_kernel<<<(NN + 1023) / 1024, 1024, 0, stream>>>(cnt, NN);
  scatter_kernel<<<(ET + 255) / 256, 256, 0, stream>>>(ei, rowptr, cnt, csr);

  // layer 1
  gemm_att_kernel<<<(NN + 63) / 64, 256, 0, stream>>>(xb, w0t, as0, ad0, hfeat, es, ed, NN);
  aggregate_kernel<<<(NN * 64 + 255) / 256, 256, 0, stream>>>((const uint4*)hfeat, es, ed, rowptr, csr, b0, h1b, NN);
  // layer 2
  gemm_att_kernel<<<(NN + 63) / 64, 256, 0, stream>>>(h1b, w1t, as1, ad1, hfeat, es, ed, NN);
  aggregate_kernel<<<(NN * 64 + 255) / 256, 256, 0, stream>>>((const uint4*)hfeat, es, ed, rowptr, csr, b1, h2b, NN);
  // head
  final_kernel<<<(NN + 63) / 64, 256, 0, stream>>>(h1b, h2b, lw, lb, out, NN);
}

// Round 11
// 359.189 us; speedup vs baseline: 10.0557x; 1.0905x over previous
//
#include <hip/hip_runtime.h>
#include <math.h>

#define NN 50000
#define E0 800000
#define ET 850000
#define NB 196   // ceil(NN/256) scan blocks
#define NBX 200  // prep: x-conversion blocks (+2 W transposes, +1 lw transpose)

typedef unsigned int uint32;
typedef unsigned short u16;
typedef __attribute__((ext_vector_type(8))) short bf16x8;  // 8 bf16 = 4 VGPRs
typedef __attribute__((ext_vector_type(4))) float f32x4;

__device__ __forceinline__ u16 f2bf(float f) {
  uint32 u = __float_as_uint(f);
  return (u16)((u + 0x7FFFu + ((u >> 16) & 1u)) >> 16);  // RNE
}
__device__ __forceinline__ float bflo(uint32 u) { return __uint_as_float(u << 16); }
__device__ __forceinline__ float bfhi(uint32 u) { return __uint_as_float(u & 0xFFFF0000u); }

// ---- prep: x -> bf16; W0,W1 -> bf16 transposed [n][k]; lw -> bf16 T [48][256] ----
__global__ __launch_bounds__(256) void prep_kernel(
    const float* __restrict__ x, const float* __restrict__ W0, const float* __restrict__ W1,
    const float* __restrict__ lw,
    u16* __restrict__ xb, u16* __restrict__ w0t, u16* __restrict__ w1t, u16* __restrict__ lwt)
{
  int b = blockIdx.x;
  if (b < NBX) {
    const float4* x4 = (const float4*)x;
    ushort4* xb4 = (ushort4*)xb;
    const int total = NN * 128 / 4;
    for (int i = b * 256 + threadIdx.x; i < total; i += NBX * 256) {
      float4 v = x4[i];
      ushort4 u;
      u.x = f2bf(v.x); u.y = f2bf(v.y); u.z = f2bf(v.z); u.w = f2bf(v.w);
      xb4[i] = u;
    }
  } else if (b < NBX + 2) {
    const float* W = (b == NBX) ? W0 : W1;
    u16* Wt = (b == NBX) ? w0t : w1t;
    __shared__ float tile[32][129];
    const int tid = threadIdx.x;
    for (int k0 = 0; k0 < 128; k0 += 32) {
      __syncthreads();
#pragma unroll
      for (int it = 0; it < 4; ++it) {  // 32 k-rows x 128 n, coalesced
        int q = tid + it * 256;
        int kk = q >> 5, n4 = (q & 31) * 4;
        float4 v = *(const float4*)&W[(k0 + kk) * 128 + n4];
        tile[kk][n4 + 0] = v.x; tile[kk][n4 + 1] = v.y;
        tile[kk][n4 + 2] = v.z; tile[kk][n4 + 3] = v.w;
      }
      __syncthreads();
      int n = tid >> 1, h = (tid & 1) * 16;
      __align__(16) u16 tmp[16];
#pragma unroll
      for (int j = 0; j < 16; ++j) tmp[j] = f2bf(tile[h + j][n]);
      *(uint4*)&Wt[n * 128 + k0 + h] = *(uint4*)&tmp[0];
      *(uint4*)&Wt[n * 128 + k0 + h + 8] = *(uint4*)&tmp[8];
    }
  } else {
    // lwt[j][k] = lw[k][j], j<40; rows 40..47 zero. 12288 elems, 48/thread.
    const int tid = threadIdx.x;
    for (int idx = tid; idx < 48 * 256; idx += 256) {
      int j = idx >> 8, k = idx & 255;
      lwt[idx] = (j < 40) ? f2bf(lw[k * 40 + j]) : (u16)0;
    }
  }
}

// ---------------- CSR build ----------------

__global__ void zero_int_kernel(int* __restrict__ p, int n) {
  int i = blockIdx.x * blockDim.x + threadIdx.x;
  if (i < n) p[i] = 0;
}

__global__ void count_kernel(const int* __restrict__ ei, int* __restrict__ cnt) {
  int e = blockIdx.x * blockDim.x + threadIdx.x;
  if (e >= ET) return;
  int dst = (e < E0) ? ei[E0 + e] : (e - E0);
  atomicAdd(&cnt[dst], 1);
}

__global__ __launch_bounds__(256) void scan_l1_kernel(const int* __restrict__ cnt,
                                                      int* __restrict__ rowptr,
                                                      int* __restrict__ bsum) {
  __shared__ int s[256];
  int i = blockIdx.x * 256 + threadIdx.x;
  int v = (i < NN) ? cnt[i] : 0;
  int val = v;
  s[threadIdx.x] = val;
  __syncthreads();
#pragma unroll
  for (int off = 1; off < 256; off <<= 1) {
    int t = (threadIdx.x >= (unsigned)off) ? s[threadIdx.x - off] : 0;
    __syncthreads();
    val += t;
    s[threadIdx.x] = val;
    __syncthreads();
  }
  if (i < NN) rowptr[i] = val - v;
  if (threadIdx.x == 255) bsum[blockIdx.x] = val;
}

__global__ __launch_bounds__(256) void scan_l2_kernel(const int* __restrict__ bsum,
                                                      int* __restrict__ boff,
                                                      int* __restrict__ rowptr) {
  __shared__ int s[256];
  int i = threadIdx.x;
  int v = (i < NB) ? bsum[i] : 0;
  int val = v;
  s[i] = val;
  __syncthreads();
#pragma unroll
  for (int off = 1; off < 256; off <<= 1) {
    int t = (i >= (unsigned)off) ? s[i - off] : 0;
    __syncthreads();
    val += t;
    s[i] = val;
    __syncthreads();
  }
  if (i < NB) boff[i] = val - v;
  if (i == NB - 1) rowptr[NN] = val;
}

__global__ __launch_bounds__(256) void scan_add_kernel(int* __restrict__ rowptr,
                                                       const int* __restrict__ boff) {
  int i = blockIdx.x * 256 + threadIdx.x;
  if (i < NN) rowptr[i] += boff[blockIdx.x];
}

__global__ void scatter_kernel(const int* __restrict__ ei, const int* __restrict__ rowptr,
                               int* __restrict__ cursor, int* __restrict__ csr_src) {
  int e = blockIdx.x * blockDim.x + threadIdx.x;
  if (e >= ET) return;
  int src, dst;
  if (e < E0) { src = ei[e]; dst = ei[E0 + e]; }
  else        { src = e - E0; dst = src; }
  int pos = rowptr[dst] + atomicAdd(&cursor[dst], 1);
  csr_src[pos] = src;
}

// ---------------- MFMA GEMM (Xb @ W) + attention logits ----------------
__global__ __launch_bounds__(256) void gemm_att_kernel(
    const u16* __restrict__ Xb, const u16* __restrict__ Wt,
    const float* __restrict__ avs, const float* __restrict__ avd,
    u16* __restrict__ hfeat, float* __restrict__ es, float* __restrict__ ed,
    int nnodes)
{
  __shared__ u16 Xs[64 * 136];    // 17.0 KB, padded stride 136
  __shared__ u16 Ws[128 * 136];   // 34.0 KB (reused as bf16 out-staging)
  __shared__ float es_s[2][64];
  __shared__ float ed_s[2][64];
  const int tid = threadIdx.x;
  const int wid = tid >> 6, lane = tid & 63;
  const int quad = lane >> 4, lc = lane & 15;
  const int n0 = blockIdx.x * 64;
  if (tid < 128) { es_s[tid >> 6][tid & 63] = 0.f; ed_s[tid >> 6][tid & 63] = 0.f; }

#pragma unroll
  for (int it = 0; it < 4; ++it) {    // Xs: 64 x 128 bf16
    int g = tid + it * 256;
    int r = g >> 4, c8 = (g & 15) * 8;
    uint4 v = make_uint4(0u, 0u, 0u, 0u);
    if (n0 + r < nnodes) v = *(const uint4*)&Xb[(size_t)(n0 + r) * 128 + c8];
    *(uint4*)&Xs[r * 136 + c8] = v;
  }
#pragma unroll
  for (int it = 0; it < 8; ++it) {    // Ws: 128 x 128 bf16 (transposed W)
    int g = tid + it * 256;
    int r = g >> 4, c8 = (g & 15) * 8;
    uint4 v = *(const uint4*)&Wt[r * 128 + c8];
    *(uint4*)&Ws[r * 136 + c8] = v;
  }
  __syncthreads();

  f32x4 acc[8];
#pragma unroll
  for (int t = 0; t < 8; ++t) acc[t] = (f32x4){0.f, 0.f, 0.f, 0.f};
  const int arow = wid * 16 + lc;
#pragma unroll 1
  for (int ks = 0; ks < 4; ++ks) {
    const int k0 = ks * 32 + quad * 8;
    bf16x8 a = *(const bf16x8*)&Xs[arow * 136 + k0];
#pragma unroll
    for (int t = 0; t < 8; ++t) {
      bf16x8 b = *(const bf16x8*)&Ws[(t * 16 + lc) * 136 + k0];
      acc[t] = __builtin_amdgcn_mfma_f32_16x16x32_bf16(a, b, acc[t], 0, 0, 0);
    }
  }

  // attention partials from C-fragments
  float av_s[8], av_d[8];
#pragma unroll
  for (int t = 0; t < 8; ++t) { av_s[t] = avs[t * 16 + lc]; av_d[t] = avd[t * 16 + lc]; }
#pragma unroll
  for (int r = 0; r < 4; ++r) {
    float s0 = 0.f, s1 = 0.f, d0 = 0.f, d1 = 0.f;
#pragma unroll
    for (int t = 0; t < 4; ++t) { s0 += acc[t][r] * av_s[t]; d0 += acc[t][r] * av_d[t]; }
#pragma unroll
    for (int t = 4; t < 8; ++t) { s1 += acc[t][r] * av_s[t]; d1 += acc[t][r] * av_d[t]; }
    int row = wid * 16 + quad * 4 + r;
    atomicAdd(&es_s[0][row], s0); atomicAdd(&es_s[1][row], s1);
    atomicAdd(&ed_s[0][row], d0); atomicAdd(&ed_s[1][row], d1);
  }
  __syncthreads();              // all LDS reads done -> reuse Ws for output staging
  u16* hout = Ws;               // 64 rows x stride 136
#pragma unroll
  for (int t = 0; t < 8; ++t)
#pragma unroll
    for (int r = 0; r < 4; ++r)
      hout[(wid * 16 + quad * 4 + r) * 136 + t * 16 + lc] = f2bf(acc[t][r]);
  __syncthreads();
#pragma unroll
  for (int it = 0; it < 4; ++it) {   // coalesced bf16 writeback
    int g = tid + it * 256;
    int r = g >> 4, c8 = (g & 15) * 8;
    if (n0 + r < nnodes)
      *(uint4*)&hfeat[(size_t)(n0 + r) * 128 + c8] = *(const uint4*)&hout[r * 136 + c8];
  }
  if (tid < 64) {
    int n = n0 + tid;
    if (n < nnodes) {
      es[n * 2 + 0] = es_s[0][tid]; es[n * 2 + 1] = es_s[1][tid];
      ed[n * 2 + 0] = ed_s[0][tid]; ed[n * 2 + 1] = ed_s[1][tid];
    }
  }
}

// ---------------- aggregation: one wave per node, 4 edges/iter, fused softmax ----------------
__global__ __launch_bounds__(256) void aggregate_kernel(
    const uint4* __restrict__ hfeat4, const float* __restrict__ es, const float* __restrict__ ed,
    const int* __restrict__ rowptr, const int* __restrict__ csr_src,
    const float* __restrict__ bias, u16* __restrict__ out, int nnodes)
{
  int n = (blockIdx.x * blockDim.x + threadIdx.x) >> 6;
  int lane = threadIdx.x & 63;
  if (n >= nnodes) return;
  const int eg = lane >> 4;       // edge group 0..3
  const int fl = lane & 15;       // feature lane: bf16 features fl*8..fl*8+7
  const int hd = (fl >= 8) ? 1 : 0;
  const int beg = rowptr[n], end = rowptr[n + 1];
  const int nch = (end - beg + 3) >> 2;
  const int j0 = beg + eg;
  const float edn = ed[n * 2 + hd];

  float acc[8];
#pragma unroll
  for (int t = 0; t < 8; ++t) acc[t] = 0.f;
  float den = 0.f;

  int idxA; float wA;
  {
    int j = j0;
    int jj = (j < end) ? j : beg;
    idxA = csr_src[jj];
    float e = es[idxA * 2 + hd] + edn;
    e = (e > 0.f) ? e : 0.2f * e;
    wA = (j < end) ? __expf(e) : 0.f;
  }
  for (int c = 0;;) {
    uint4 hv = hfeat4[(size_t)idxA * 16 + fl];
    bool more = (c + 1 < nch);
    int idxB; float wB;
    if (more) {
      int j = j0 + (c + 1) * 4;
      int jj = (j < end) ? j : beg;
      idxB = csr_src[jj];
      float e = es[idxB * 2 + hd] + edn;
      e = (e > 0.f) ? e : 0.2f * e;
      wB = (j < end) ? __expf(e) : 0.f;
    }
    acc[0] = fmaf(wA, bflo(hv.x), acc[0]);
    acc[1] = fmaf(wA, bfhi(hv.x), acc[1]);
    acc[2] = fmaf(wA, bflo(hv.y), acc[2]);
    acc[3] = fmaf(wA, bfhi(hv.y), acc[3]);
    acc[4] = fmaf(wA, bflo(hv.z), acc[4]);
    acc[5] = fmaf(wA, bfhi(hv.z), acc[5]);
    acc[6] = fmaf(wA, bflo(hv.w), acc[6]);
    acc[7] = fmaf(wA, bfhi(hv.w), acc[7]);
    den += wA;
    if (!more) break;
    idxA = idxB; wA = wB;
    ++c;
  }

#pragma unroll
  for (int t = 0; t < 8; ++t) {
    acc[t] += __shfl_xor(acc[t], 16);
    acc[t] += __shfl_xor(acc[t], 32);
  }
  den += __shfl_xor(den, 16);
  den += __shfl_xor(den, 32);

  if (eg == 0) {
    float inv = 1.f / den;
    float4 b0 = *(const float4*)&bias[fl * 8];
    float4 b1 = *(const float4*)&bias[fl * 8 + 4];
    float bv[8] = {b0.x, b0.y, b0.z, b0.w, b1.x, b1.y, b1.z, b1.w};
    u16 pk[8];
#pragma unroll
    for (int t = 0; t < 8; ++t) {
      float v = acc[t] * inv + bv[t];
      v = (v > 0.f) ? v : (__expf(v) - 1.f);  // ELU
      pk[t] = f2bf(v);
    }
    uint4 o;
    o.x = (uint32)pk[0] | ((uint32)pk[1] << 16);
    o.y = (uint32)pk[2] | ((uint32)pk[3] << 16);
    o.z = (uint32)pk[4] | ((uint32)pk[5] << 16);
    o.w = (uint32)pk[6] | ((uint32)pk[7] << 16);
    ((uint4*)out)[(size_t)n * 16 + fl] = o;
  }
}

// ---------------- final: MFMA [64x256] @ [256x48] + log_softmax on fragments ----------------
// Wave w: rows 16w..16w+15, 3 N-tiles (48 cols, 40 valid). C/D: col=lc, row=quad*4+r.
// log_softmax per row: butterfly over the 16 lanes of a quad (xor 1,2,4,8).
#define FS 264  // LDS row stride in bf16 (528 B: 16B-aligned, 132 dw -> banks spread)
__global__ __launch_bounds__(256) void final_kernel(
    const u16* __restrict__ h1b, const u16* __restrict__ h2b,
    const u16* __restrict__ lwt, const float* __restrict__ lb,
    float* __restrict__ out, int nnodes)
{
  __shared__ u16 Hs[64 * FS];   // 33.8 KB
  __shared__ u16 Ls[48 * FS];   // 25.3 KB
  const int tid = threadIdx.x;
  const int wid = tid >> 6, lane = tid & 63;
  const int quad = lane >> 4, lc = lane & 15;
  const int n0 = blockIdx.x * 64;

#pragma unroll
  for (int it = 0; it < 8; ++it) {    // Hs: 64 rows x 256 bf16 (h1|h2 concat)
    int g = tid + it * 256;
    int r = g >> 5, c8 = (g & 31) * 8;
    uint4 v = make_uint4(0u, 0u, 0u, 0u);
    if (n0 + r < nnodes) {
      const u16* src = (c8 < 128) ? &h1b[(size_t)(n0 + r) * 128 + c8]
                                  : &h2b[(size_t)(n0 + r) * 128 + (c8 - 128)];
      v = *(const uint4*)src;
    }
    *(uint4*)&Hs[r * FS + c8] = v;
  }
#pragma unroll
  for (int it = 0; it < 6; ++it) {    // Ls: 48 rows x 256 bf16 (lw^T, rows>=40 zero)
    int g = tid + it * 256;
    int r = g >> 5, c8 = (g & 31) * 8;
    *(uint4*)&Ls[r * FS + c8] = *(const uint4*)&lwt[r * 256 + c8];
  }
  __syncthreads();

  f32x4 acc[3];
#pragma unroll
  for (int t = 0; t < 3; ++t) acc[t] = (f32x4){0.f, 0.f, 0.f, 0.f};
  const int arow = wid * 16 + lc;
#pragma unroll
  for (int ks = 0; ks < 8; ++ks) {
    const int k0 = ks * 32 + quad * 8;
    bf16x8 a = *(const bf16x8*)&Hs[arow * FS + k0];
#pragma unroll
    for (int t = 0; t < 3; ++t) {
      bf16x8 b = *(const bf16x8*)&Ls[(t * 16 + lc) * FS + k0];
      acc[t] = __builtin_amdgcn_mfma_f32_16x16x32_bf16(a, b, acc[t], 0, 0, 0);
    }
  }

  // bias + log_softmax per row (col = t*16+lc valid iff < 40)
  float bv[3];
  bool valid[3];
#pragma unroll
  for (int t = 0; t < 3; ++t) {
    int col = t * 16 + lc;
    valid[t] = (col < 40);
    bv[t] = valid[t] ? lb[col] : 0.f;
  }
#pragma unroll
  for (int r = 0; r < 4; ++r) {
    int row = wid * 16 + quad * 4 + r;
    int n = n0 + row;
    float v[3];
    float mx = -INFINITY;
#pragma unroll
    for (int t = 0; t < 3; ++t) {
      v[t] = acc[t][r] + bv[t];
      if (valid[t]) mx = fmaxf(mx, v[t]);
    }
    mx = fmaxf(mx, __shfl_xor(mx, 1));
    mx = fmaxf(mx, __shfl_xor(mx, 2));
    mx = fmaxf(mx, __shfl_xor(mx, 4));
    mx = fmaxf(mx, __shfl_xor(mx, 8));
    float s = 0.f;
#pragma unroll
    for (int t = 0; t < 3; ++t) if (valid[t]) s += __expf(v[t] - mx);
    s += __shfl_xor(s, 1);
    s += __shfl_xor(s, 2);
    s += __shfl_xor(s, 4);
    s += __shfl_xor(s, 8);
    float lg = mx + __logf(s);
    if (n < nnodes) {
#pragma unroll
      for (int t = 0; t < 3; ++t)
        if (valid[t]) out[(size_t)n * 40 + t * 16 + lc] = v[t] - lg;
    }
  }
}

// ---------------- launch ----------------

extern "C" void kernel_launch(void* const* d_in, const int* in_sizes, int n_in,
                              void* d_out, int out_size, void* d_ws, size_t ws_size,
                              hipStream_t stream) {
  const float* x   = (const float*)d_in[0];
  const int*   ei  = (const int*)d_in[1];
  const float* W0  = (const float*)d_in[2];
  const float* as0 = (const float*)d_in[3];
  const float* ad0 = (const float*)d_in[4];
  const float* b0  = (const float*)d_in[5];
  const float* W1  = (const float*)d_in[6];
  const float* as1 = (const float*)d_in[7];
  const float* ad1 = (const float*)d_in[8];
  const float* b1  = (const float*)d_in[9];
  const float* lw  = (const float*)d_in[10];
  const float* lb  = (const float*)d_in[11];
  float* out = (float*)d_out;

  char* p = (char*)d_ws;
  auto carve = [&](size_t bytes) { char* r = p; p += (bytes + 255) & ~(size_t)255; return r; };
  u16* xb     = (u16*)carve((size_t)NN * 128 * 2);
  u16* w0t    = (u16*)carve(128 * 128 * 2);
  u16* w1t    = (u16*)carve(128 * 128 * 2);
  u16* lwt    = (u16*)carve(48 * 256 * 2);
  u16* hfeat  = (u16*)carve((size_t)NN * 128 * 2);
  u16* h1b    = (u16*)carve((size_t)NN * 128 * 2);
  u16* h2b    = (u16*)carve((size_t)NN * 128 * 2);
  float* es   = (float*)carve((size_t)NN * 2 * 4);
  float* ed   = (float*)carve((size_t)NN * 2 * 4);
  int* rowptr = (int*)carve((size_t)(NN + 1) * 4);
  int* cnt    = (int*)carve((size_t)NN * 4);
  int* csr    = (int*)carve((size_t)ET * 4);
  int* bsum   = (int*)carve((size_t)NB * 4);
  int* boff   = (int*)carve((size_t)NB * 4);

  // prep (bf16 conversions + transposes)
  prep_kernel<<<NBX + 3, 256, 0, stream>>>(x, W0, W1, lw, xb, w0t, w1t, lwt);

  // CSR build (reused by both layers)
  zero_int_kernel<<<(NN + 1023) / 1024, 1024, 0, stream>>>(cnt, NN);
  count_kernel<<<(ET + 255) / 256, 256, 0, stream>>>(ei, cnt);
  scan_l1_kernel<<<NB, 256, 0, stream>>>(cnt, rowptr, bsum);
  scan_l2_kernel<<<1, 256, 0, stream>>>(bsum, boff, rowptr);
  scan_add_kernel<<<NB, 256, 0, stream>>>(rowptr, boff);
  zero_int_kernel<<<(NN + 1023) / 1024, 1024, 0, stream>>>(cnt, NN);
  scatter_kernel<<<(ET + 255) / 256, 256, 0, stream>>>(ei, rowptr, cnt, csr);

  // layer 1
  gemm_att_kernel<<<(NN + 63) / 64, 256, 0, stream>>>(xb, w0t, as0, ad0, hfeat, es, ed, NN);
  aggregate_kernel<<<(NN * 64 + 255) / 256, 256, 0, stream>>>((const uint4*)hfeat, es, ed, rowptr, csr, b0, h1b, NN);
  // layer 2
  gemm_att_kernel<<<(NN + 63) / 64, 256, 0, stream>>>(h1b, w1t, as1, ad1, hfeat, es, ed, NN);
  aggregate_kernel<<<(NN * 64 + 255) / 256, 256, 0, stream>>>((const uint4*)hfeat, es, ed, rowptr, csr, b1, h2b, NN);
  // head
  final_kernel<<<(NN + 63) / 64, 256, 0, stream>>>(h1b, h2b, lwt, lb, out, NN);
}

// Round 12
// 298.635 us; speedup vs baseline: 12.0947x; 1.2028x over previous
//
#include <hip/hip_runtime.h>
#include <math.h>

#define NN 50000
#define E0 800000
#define ET 850000
#define NBX 200  // prep: x-conversion blocks (+2 W transposes, +1 lw transpose)
#define NBK 196  // CSR buckets = ceil(NN/256), 256 nodes each
#define TILE 4096
#define NTILES 208  // ceil(ET/TILE)
#define CAP 8192    // per-bucket capacity in packed buf (mean 4352, sigma ~66)

typedef unsigned int uint32;
typedef unsigned short u16;
typedef __attribute__((ext_vector_type(8))) short bf16x8;  // 8 bf16 = 4 VGPRs
typedef __attribute__((ext_vector_type(4))) float f32x4;

__device__ __forceinline__ u16 f2bf(float f) {
  uint32 u = __float_as_uint(f);
  return (u16)((u + 0x7FFFu + ((u >> 16) & 1u)) >> 16);  // RNE
}
__device__ __forceinline__ float bflo(uint32 u) { return __uint_as_float(u << 16); }
__device__ __forceinline__ float bfhi(uint32 u) { return __uint_as_float(u & 0xFFFF0000u); }

// ---- prep: x -> bf16; W0,W1 -> bf16 transposed [n][k]; lw -> bf16 T [48][256] ----
__global__ __launch_bounds__(256) void prep_kernel(
    const float* __restrict__ x, const float* __restrict__ W0, const float* __restrict__ W1,
    const float* __restrict__ lw,
    u16* __restrict__ xb, u16* __restrict__ w0t, u16* __restrict__ w1t, u16* __restrict__ lwt)
{
  int b = blockIdx.x;
  if (b < NBX) {
    const float4* x4 = (const float4*)x;
    ushort4* xb4 = (ushort4*)xb;
    const int total = NN * 128 / 4;
    for (int i = b * 256 + threadIdx.x; i < total; i += NBX * 256) {
      float4 v = x4[i];
      ushort4 u;
      u.x = f2bf(v.x); u.y = f2bf(v.y); u.z = f2bf(v.z); u.w = f2bf(v.w);
      xb4[i] = u;
    }
  } else if (b < NBX + 2) {
    const float* W = (b == NBX) ? W0 : W1;
    u16* Wt = (b == NBX) ? w0t : w1t;
    __shared__ float tile[32][129];
    const int tid = threadIdx.x;
    for (int k0 = 0; k0 < 128; k0 += 32) {
      __syncthreads();
#pragma unroll
      for (int it = 0; it < 4; ++it) {
        int q = tid + it * 256;
        int kk = q >> 5, n4 = (q & 31) * 4;
        float4 v = *(const float4*)&W[(k0 + kk) * 128 + n4];
        tile[kk][n4 + 0] = v.x; tile[kk][n4 + 1] = v.y;
        tile[kk][n4 + 2] = v.z; tile[kk][n4 + 3] = v.w;
      }
      __syncthreads();
      int n = tid >> 1, h = (tid & 1) * 16;
      __align__(16) u16 tmp[16];
#pragma unroll
      for (int j = 0; j < 16; ++j) tmp[j] = f2bf(tile[h + j][n]);
      *(uint4*)&Wt[n * 128 + k0 + h] = *(uint4*)&tmp[0];
      *(uint4*)&Wt[n * 128 + k0 + h + 8] = *(uint4*)&tmp[8];
    }
  } else {
    const int tid = threadIdx.x;
    for (int idx = tid; idx < 48 * 256; idx += 256) {
      int j = idx >> 8, k = idx & 255;
      lwt[idx] = (j < 40) ? f2bf(lw[k * 40 + j]) : (u16)0;
    }
  }
}

// ---------------- CSR build: binned two-pass (no random 4B scatter) ----------------

__global__ void zero_int_kernel(int* __restrict__ p, int n) {
  int i = blockIdx.x * blockDim.x + threadIdx.x;
  if (i < n) p[i] = 0;
}

// Pass 1: tile-local histogram+reorder in LDS, flush bucket-runs to packed buf.
__global__ __launch_bounds__(256) void partition_kernel(
    const int* __restrict__ ei, int* __restrict__ gcursor, uint32* __restrict__ packed)
{
  __shared__ int hist[NBK];
  __shared__ int s[256];
  __shared__ int scanb[NBK];
  __shared__ int gofs[NBK];
  __shared__ uint32 shuf[TILE];
  __shared__ unsigned char sbkt[TILE];
  const int tid = threadIdx.x;
  const int t0 = blockIdx.x * TILE;
  for (int i = tid; i < NBK; i += 256) hist[i] = 0;
  __syncthreads();
  int myb[16]; int myr[16]; uint32 mypk[16];
#pragma unroll
  for (int i = 0; i < 16; ++i) {
    int e = t0 + i * 256 + tid;
    myb[i] = -1;
    if (e < ET) {
      int src, dst;
      if (e < E0) { src = ei[e]; dst = ei[E0 + e]; }
      else        { src = e - E0; dst = src; }
      myb[i] = dst >> 8;
      mypk[i] = ((uint32)(dst & 255) << 16) | (uint32)src;
      myr[i] = atomicAdd(&hist[myb[i]], 1);
    }
  }
  __syncthreads();
  // exclusive scan of hist over 256 slots
  int v = (tid < NBK) ? hist[tid] : 0;
  int val = v;
  s[tid] = val;
  __syncthreads();
#pragma unroll
  for (int off = 1; off < 256; off <<= 1) {
    int t = (tid >= off) ? s[tid - off] : 0;
    __syncthreads();
    val += t;
    s[tid] = val;
    __syncthreads();
  }
  if (tid < NBK) {
    scanb[tid] = val - v;
    gofs[tid] = (v > 0) ? atomicAdd(&gcursor[tid], v) : 0;
  }
  __syncthreads();
#pragma unroll
  for (int i = 0; i < 16; ++i) {
    if (myb[i] >= 0) {
      int slot = scanb[myb[i]] + myr[i];
      shuf[slot] = mypk[i];
      sbkt[slot] = (unsigned char)myb[i];
    }
  }
  __syncthreads();
  const int tcount = (t0 + TILE <= ET) ? TILE : (ET - t0);
  for (int i = tid; i < tcount; i += 256) {
    int b = sbkt[i];
    packed[(size_t)b * CAP + gofs[b] + (i - scanb[b])] = shuf[i];
  }
}

// scan of 196 bucket totals -> bases; rowptr[NN] = ET
__global__ __launch_bounds__(256) void bucket_scan_kernel(
    const int* __restrict__ gcursor, int* __restrict__ bbase, int* __restrict__ rowptr)
{
  __shared__ int s[256];
  int i = threadIdx.x;
  int v = (i < NBK) ? gcursor[i] : 0;
  int val = v;
  s[i] = val;
  __syncthreads();
#pragma unroll
  for (int off = 1; off < 256; off <<= 1) {
    int t = (i >= off) ? s[i - off] : 0;
    __syncthreads();
    val += t;
    s[i] = val;
    __syncthreads();
  }
  if (i < NBK) bbase[i] = val - v;
  if (i == 255) rowptr[NN] = s[255];
}

// Pass 2: per bucket, local CSR in LDS, coalesced rowptr + csr_src writes.
__global__ __launch_bounds__(256) void build_kernel(
    const uint32* __restrict__ packed, const int* __restrict__ gcursor,
    const int* __restrict__ bbase, int* __restrict__ rowptr, int* __restrict__ csr_src)
{
  __shared__ int h[256];
  __shared__ int s[256];
  __shared__ int sc[256];
  __shared__ int cur[256];
  __shared__ u16 simg[CAP];
  const int b = blockIdx.x;
  const int tid = threadIdx.x;
  const int cnt = gcursor[b];
  const int base = bbase[b];
  const uint32* pk = packed + (size_t)b * CAP;
  h[tid] = 0;
  cur[tid] = 0;
  __syncthreads();
  for (int i = tid; i < cnt; i += 256) atomicAdd(&h[(pk[i] >> 16) & 255], 1);
  __syncthreads();
  int v = h[tid];
  int val = v;
  s[tid] = val;
  __syncthreads();
#pragma unroll
  for (int off = 1; off < 256; off <<= 1) {
    int t = (tid >= off) ? s[tid - off] : 0;
    __syncthreads();
    val += t;
    s[tid] = val;
    __syncthreads();
  }
  sc[tid] = val - v;
  __syncthreads();
  for (int i = tid; i < cnt; i += 256) {
    uint32 p = pk[i];
    int dl = (p >> 16) & 255;
    int r = atomicAdd(&cur[dl], 1);
    simg[sc[dl] + r] = (u16)(p & 0xFFFFu);
  }
  __syncthreads();
  int n = b * 256 + tid;
  if (n < NN) rowptr[n] = base + sc[tid];
  for (int i = tid; i < cnt; i += 256) csr_src[base + i] = (int)simg[i];
}

// ---------------- MFMA GEMM (Xb @ W) + attention logits ----------------
__global__ __launch_bounds__(256) void gemm_att_kernel(
    const u16* __restrict__ Xb, const u16* __restrict__ Wt,
    const float* __restrict__ avs, const float* __restrict__ avd,
    u16* __restrict__ hfeat, float* __restrict__ es, float* __restrict__ ed,
    int nnodes)
{
  __shared__ u16 Xs[64 * 136];    // 17.0 KB, padded stride 136
  __shared__ u16 Ws[128 * 136];   // 34.0 KB (reused as bf16 out-staging)
  __shared__ float es_s[2][64];
  __shared__ float ed_s[2][64];
  const int tid = threadIdx.x;
  const int wid = tid >> 6, lane = tid & 63;
  const int quad = lane >> 4, lc = lane & 15;
  const int n0 = blockIdx.x * 64;
  if (tid < 128) { es_s[tid >> 6][tid & 63] = 0.f; ed_s[tid >> 6][tid & 63] = 0.f; }

#pragma unroll
  for (int it = 0; it < 4; ++it) {    // Xs: 64 x 128 bf16
    int g = tid + it * 256;
    int r = g >> 4, c8 = (g & 15) * 8;
    uint4 v = make_uint4(0u, 0u, 0u, 0u);
    if (n0 + r < nnodes) v = *(const uint4*)&Xb[(size_t)(n0 + r) * 128 + c8];
    *(uint4*)&Xs[r * 136 + c8] = v;
  }
#pragma unroll
  for (int it = 0; it < 8; ++it) {    // Ws: 128 x 128 bf16 (transposed W)
    int g = tid + it * 256;
    int r = g >> 4, c8 = (g & 15) * 8;
    uint4 v = *(const uint4*)&Wt[r * 128 + c8];
    *(uint4*)&Ws[r * 136 + c8] = v;
  }
  __syncthreads();

  f32x4 acc[8];
#pragma unroll
  for (int t = 0; t < 8; ++t) acc[t] = (f32x4){0.f, 0.f, 0.f, 0.f};
  const int arow = wid * 16 + lc;
#pragma unroll 1
  for (int ks = 0; ks < 4; ++ks) {
    const int k0 = ks * 32 + quad * 8;
    bf16x8 a = *(const bf16x8*)&Xs[arow * 136 + k0];
#pragma unroll
    for (int t = 0; t < 8; ++t) {
      bf16x8 b = *(const bf16x8*)&Ws[(t * 16 + lc) * 136 + k0];
      acc[t] = __builtin_amdgcn_mfma_f32_16x16x32_bf16(a, b, acc[t], 0, 0, 0);
    }
  }

  float av_s[8], av_d[8];
#pragma unroll
  for (int t = 0; t < 8; ++t) { av_s[t] = avs[t * 16 + lc]; av_d[t] = avd[t * 16 + lc]; }
#pragma unroll
  for (int r = 0; r < 4; ++r) {
    float s0 = 0.f, s1 = 0.f, d0 = 0.f, d1 = 0.f;
#pragma unroll
    for (int t = 0; t < 4; ++t) { s0 += acc[t][r] * av_s[t]; d0 += acc[t][r] * av_d[t]; }
#pragma unroll
    for (int t = 4; t < 8; ++t) { s1 += acc[t][r] * av_s[t]; d1 += acc[t][r] * av_d[t]; }
    int row = wid * 16 + quad * 4 + r;
    atomicAdd(&es_s[0][row], s0); atomicAdd(&es_s[1][row], s1);
    atomicAdd(&ed_s[0][row], d0); atomicAdd(&ed_s[1][row], d1);
  }
  __syncthreads();
  u16* hout = Ws;
#pragma unroll
  for (int t = 0; t < 8; ++t)
#pragma unroll
    for (int r = 0; r < 4; ++r)
      hout[(wid * 16 + quad * 4 + r) * 136 + t * 16 + lc] = f2bf(acc[t][r]);
  __syncthreads();
#pragma unroll
  for (int it = 0; it < 4; ++it) {
    int g = tid + it * 256;
    int r = g >> 4, c8 = (g & 15) * 8;
    if (n0 + r < nnodes)
      *(uint4*)&hfeat[(size_t)(n0 + r) * 128 + c8] = *(const uint4*)&hout[r * 136 + c8];
  }
  if (tid < 64) {
    int n = n0 + tid;
    if (n < nnodes) {
      es[n * 2 + 0] = es_s[0][tid]; es[n * 2 + 1] = es_s[1][tid];
      ed[n * 2 + 0] = ed_s[0][tid]; ed[n * 2 + 1] = ed_s[1][tid];
    }
  }
}

// ---------------- aggregation: one wave per node, 4 edges/iter, fused softmax ----------------
__global__ __launch_bounds__(256) void aggregate_kernel(
    const uint4* __restrict__ hfeat4, const float* __restrict__ es, const float* __restrict__ ed,
    const int* __restrict__ rowptr, const int* __restrict__ csr_src,
    const float* __restrict__ bias, u16* __restrict__ out, int nnodes)
{
  int n = (blockIdx.x * blockDim.x + threadIdx.x) >> 6;
  int lane = threadIdx.x & 63;
  if (n >= nnodes) return;
  const int eg = lane >> 4;
  const int fl = lane & 15;
  const int hd = (fl >= 8) ? 1 : 0;
  const int beg = rowptr[n], end = rowptr[n + 1];
  const int nch = (end - beg + 3) >> 2;
  const int j0 = beg + eg;
  const float edn = ed[n * 2 + hd];

  float acc[8];
#pragma unroll
  for (int t = 0; t < 8; ++t) acc[t] = 0.f;
  float den = 0.f;

  int idxA; float wA;
  {
    int j = j0;
    int jj = (j < end) ? j : beg;
    idxA = csr_src[jj];
    float e = es[idxA * 2 + hd] + edn;
    e = (e > 0.f) ? e : 0.2f * e;
    wA = (j < end) ? __expf(e) : 0.f;
  }
  for (int c = 0;;) {
    uint4 hv = hfeat4[(size_t)idxA * 16 + fl];
    bool more = (c + 1 < nch);
    int idxB; float wB;
    if (more) {
      int j = j0 + (c + 1) * 4;
      int jj = (j < end) ? j : beg;
      idxB = csr_src[jj];
      float e = es[idxB * 2 + hd] + edn;
      e = (e > 0.f) ? e : 0.2f * e;
      wB = (j < end) ? __expf(e) : 0.f;
    }
    acc[0] = fmaf(wA, bflo(hv.x), acc[0]);
    acc[1] = fmaf(wA, bfhi(hv.x), acc[1]);
    acc[2] = fmaf(wA, bflo(hv.y), acc[2]);
    acc[3] = fmaf(wA, bfhi(hv.y), acc[3]);
    acc[4] = fmaf(wA, bflo(hv.z), acc[4]);
    acc[5] = fmaf(wA, bfhi(hv.z), acc[5]);
    acc[6] = fmaf(wA, bflo(hv.w), acc[6]);
    acc[7] = fmaf(wA, bfhi(hv.w), acc[7]);
    den += wA;
    if (!more) break;
    idxA = idxB; wA = wB;
    ++c;
  }

#pragma unroll
  for (int t = 0; t < 8; ++t) {
    acc[t] += __shfl_xor(acc[t], 16);
    acc[t] += __shfl_xor(acc[t], 32);
  }
  den += __shfl_xor(den, 16);
  den += __shfl_xor(den, 32);

  if (eg == 0) {
    float inv = 1.f / den;
    float4 b0 = *(const float4*)&bias[fl * 8];
    float4 b1 = *(const float4*)&bias[fl * 8 + 4];
    float bv[8] = {b0.x, b0.y, b0.z, b0.w, b1.x, b1.y, b1.z, b1.w};
    u16 pk[8];
#pragma unroll
    for (int t = 0; t < 8; ++t) {
      float v = acc[t] * inv + bv[t];
      v = (v > 0.f) ? v : (__expf(v) - 1.f);  // ELU
      pk[t] = f2bf(v);
    }
    uint4 o;
    o.x = (uint32)pk[0] | ((uint32)pk[1] << 16);
    o.y = (uint32)pk[2] | ((uint32)pk[3] << 16);
    o.z = (uint32)pk[4] | ((uint32)pk[5] << 16);
    o.w = (uint32)pk[6] | ((uint32)pk[7] << 16);
    ((uint4*)out)[(size_t)n * 16 + fl] = o;
  }
}

// ---------------- final: MFMA [64x256] @ [256x48] + log_softmax on fragments ----------------
#define FS 264
__global__ __launch_bounds__(256) void final_kernel(
    const u16* __restrict__ h1b, const u16* __restrict__ h2b,
    const u16* __restrict__ lwt, const float* __restrict__ lb,
    float* __restrict__ out, int nnodes)
{
  __shared__ u16 Hs[64 * FS];
  __shared__ u16 Ls[48 * FS];
  const int tid = threadIdx.x;
  const int wid = tid >> 6, lane = tid & 63;
  const int quad = lane >> 4, lc = lane & 15;
  const int n0 = blockIdx.x * 64;

#pragma unroll
  for (int it = 0; it < 8; ++it) {
    int g = tid + it * 256;
    int r = g >> 5, c8 = (g & 31) * 8;
    uint4 v = make_uint4(0u, 0u, 0u, 0u);
    if (n0 + r < nnodes) {
      const u16* src = (c8 < 128) ? &h1b[(size_t)(n0 + r) * 128 + c8]
                                  : &h2b[(size_t)(n0 + r) * 128 + (c8 - 128)];
      v = *(const uint4*)src;
    }
    *(uint4*)&Hs[r * FS + c8] = v;
  }
#pragma unroll
  for (int it = 0; it < 6; ++it) {
    int g = tid + it * 256;
    int r = g >> 5, c8 = (g & 31) * 8;
    *(uint4*)&Ls[r * FS + c8] = *(const uint4*)&lwt[r * 256 + c8];
  }
  __syncthreads();

  f32x4 acc[3];
#pragma unroll
  for (int t = 0; t < 3; ++t) acc[t] = (f32x4){0.f, 0.f, 0.f, 0.f};
  const int arow = wid * 16 + lc;
#pragma unroll
  for (int ks = 0; ks < 8; ++ks) {
    const int k0 = ks * 32 + quad * 8;
    bf16x8 a = *(const bf16x8*)&Hs[arow * FS + k0];
#pragma unroll
    for (int t = 0; t < 3; ++t) {
      bf16x8 b = *(const bf16x8*)&Ls[(t * 16 + lc) * FS + k0];
      acc[t] = __builtin_amdgcn_mfma_f32_16x16x32_bf16(a, b, acc[t], 0, 0, 0);
    }
  }

  float bv[3];
  bool valid[3];
#pragma unroll
  for (int t = 0; t < 3; ++t) {
    int col = t * 16 + lc;
    valid[t] = (col < 40);
    bv[t] = valid[t] ? lb[col] : 0.f;
  }
#pragma unroll
  for (int r = 0; r < 4; ++r) {
    int row = wid * 16 + quad * 4 + r;
    int n = n0 + row;
    float v[3];
    float mx = -INFINITY;
#pragma unroll
    for (int t = 0; t < 3; ++t) {
      v[t] = acc[t][r] + bv[t];
      if (valid[t]) mx = fmaxf(mx, v[t]);
    }
    mx = fmaxf(mx, __shfl_xor(mx, 1));
    mx = fmaxf(mx, __shfl_xor(mx, 2));
    mx = fmaxf(mx, __shfl_xor(mx, 4));
    mx = fmaxf(mx, __shfl_xor(mx, 8));
    float s = 0.f;
#pragma unroll
    for (int t = 0; t < 3; ++t) if (valid[t]) s += __expf(v[t] - mx);
    s += __shfl_xor(s, 1);
    s += __shfl_xor(s, 2);
    s += __shfl_xor(s, 4);
    s += __shfl_xor(s, 8);
    float lg = mx + __logf(s);
    if (n < nnodes) {
#pragma unroll
      for (int t = 0; t < 3; ++t)
        if (valid[t]) out[(size_t)n * 40 + t * 16 + lc] = v[t] - lg;
    }
  }
}

// ---------------- launch ----------------

extern "C" void kernel_launch(void* const* d_in, const int* in_sizes, int n_in,
                              void* d_out, int out_size, void* d_ws, size_t ws_size,
                              hipStream_t stream) {
  const float* x   = (const float*)d_in[0];
  const int*   ei  = (const int*)d_in[1];
  const float* W0  = (const float*)d_in[2];
  const float* as0 = (const float*)d_in[3];
  const float* ad0 = (const float*)d_in[4];
  const float* b0  = (const float*)d_in[5];
  const float* W1  = (const float*)d_in[6];
  const float* as1 = (const float*)d_in[7];
  const float* ad1 = (const float*)d_in[8];
  const float* b1  = (const float*)d_in[9];
  const float* lw  = (const float*)d_in[10];
  const float* lb  = (const float*)d_in[11];
  float* out = (float*)d_out;

  char* p = (char*)d_ws;
  auto carve = [&](size_t bytes) { char* r = p; p += (bytes + 255) & ~(size_t)255; return r; };
  u16* xb     = (u16*)carve((size_t)NN * 128 * 2);
  u16* w0t    = (u16*)carve(128 * 128 * 2);
  u16* w1t    = (u16*)carve(128 * 128 * 2);
  u16* lwt    = (u16*)carve(48 * 256 * 2);
  u16* hfeat  = (u16*)carve((size_t)NN * 128 * 2);
  u16* h1b    = (u16*)carve((size_t)NN * 128 * 2);
  u16* h2b    = (u16*)carve((size_t)NN * 128 * 2);
  float* es   = (float*)carve((size_t)NN * 2 * 4);
  float* ed   = (float*)carve((size_t)NN * 2 * 4);
  int* rowptr = (int*)carve((size_t)(NN + 1) * 4);
  int* csr    = (int*)carve((size_t)ET * 4);
  uint32* packed = (uint32*)carve((size_t)NBK * CAP * 4);
  int* gcursor = (int*)carve(NBK * 4);
  int* bbase   = (int*)carve(NBK * 4);

  // prep (bf16 conversions + transposes)
  prep_kernel<<<NBX + 3, 256, 0, stream>>>(x, W0, W1, lw, xb, w0t, w1t, lwt);

  // CSR build: binned two-pass
  zero_int_kernel<<<1, 256, 0, stream>>>(gcursor, NBK);
  partition_kernel<<<NTILES, 256, 0, stream>>>(ei, gcursor, packed);
  bucket_scan_kernel<<<1, 256, 0, stream>>>(gcursor, bbase, rowptr);
  build_kernel<<<NBK, 256, 0, stream>>>(packed, gcursor, bbase, rowptr, csr);

  // layer 1
  gemm_att_kernel<<<(NN + 63) / 64, 256, 0, stream>>>(xb, w0t, as0, ad0, hfeat, es, ed, NN);
  aggregate_kernel<<<(NN * 64 + 255) / 256, 256, 0, stream>>>((const uint4*)hfeat, es, ed, rowptr, csr, b0, h1b, NN);
  // layer 2
  gemm_att_kernel<<<(NN + 63) / 64, 256, 0, stream>>>(h1b, w1t, as1, ad1, hfeat, es, ed, NN);
  aggregate_kernel<<<(NN * 64 + 255) / 256, 256, 0, stream>>>((const uint4*)hfeat, es, ed, rowptr, csr, b1, h2b, NN);
  // head
  final_kernel<<<(NN + 63) / 64, 256, 0, stream>>>(h1b, h2b, lwt, lb, out, NN);
}

// Round 13
// 279.866 us; speedup vs baseline: 12.9058x; 1.0671x over previous
//
#include <hip/hip_runtime.h>
#include <math.h>

#define NN 50000
#define E0 800000
#define ET 850000
#define NBX 200  // prep: x-conversion blocks (+2 W transposes, +1 lw transpose)
#define NBK 196  // CSR buckets = ceil(NN/256), 256 nodes each
#define TILE 4096
#define NTILES 208  // ceil(ET/TILE)
#define CAP 8192    // per-bucket region (packed & padded csr); padded mean ~5250, max ~5900

typedef unsigned int uint32;
typedef unsigned short u16;
typedef __attribute__((ext_vector_type(8))) short bf16x8;  // 8 bf16 = 4 VGPRs
typedef __attribute__((ext_vector_type(4))) float f32x4;

__device__ __forceinline__ u16 f2bf(float f) {
  uint32 u = __float_as_uint(f);
  return (u16)((u + 0x7FFFu + ((u >> 16) & 1u)) >> 16);  // RNE
}
__device__ __forceinline__ float bflo(uint32 u) { return __uint_as_float(u << 16); }
__device__ __forceinline__ float bfhi(uint32 u) { return __uint_as_float(u & 0xFFFF0000u); }

// ---- prep: x -> bf16; W0,W1 -> bf16 transposed [n][k]; lw -> bf16 T [48][256] ----
__global__ __launch_bounds__(256) void prep_kernel(
    const float* __restrict__ x, const float* __restrict__ W0, const float* __restrict__ W1,
    const float* __restrict__ lw,
    u16* __restrict__ xb, u16* __restrict__ w0t, u16* __restrict__ w1t, u16* __restrict__ lwt)
{
  int b = blockIdx.x;
  if (b < NBX) {
    const float4* x4 = (const float4*)x;
    ushort4* xb4 = (ushort4*)xb;
    const int total = NN * 128 / 4;
    for (int i = b * 256 + threadIdx.x; i < total; i += NBX * 256) {
      float4 v = x4[i];
      ushort4 u;
      u.x = f2bf(v.x); u.y = f2bf(v.y); u.z = f2bf(v.z); u.w = f2bf(v.w);
      xb4[i] = u;
    }
  } else if (b < NBX + 2) {
    const float* W = (b == NBX) ? W0 : W1;
    u16* Wt = (b == NBX) ? w0t : w1t;
    __shared__ float tile[32][129];
    const int tid = threadIdx.x;
    for (int k0 = 0; k0 < 128; k0 += 32) {
      __syncthreads();
#pragma unroll
      for (int it = 0; it < 4; ++it) {
        int q = tid + it * 256;
        int kk = q >> 5, n4 = (q & 31) * 4;
        float4 v = *(const float4*)&W[(k0 + kk) * 128 + n4];
        tile[kk][n4 + 0] = v.x; tile[kk][n4 + 1] = v.y;
        tile[kk][n4 + 2] = v.z; tile[kk][n4 + 3] = v.w;
      }
      __syncthreads();
      int n = tid >> 1, h = (tid & 1) * 16;
      __align__(16) u16 tmp[16];
#pragma unroll
      for (int j = 0; j < 16; ++j) tmp[j] = f2bf(tile[h + j][n]);
      *(uint4*)&Wt[n * 128 + k0 + h] = *(uint4*)&tmp[0];
      *(uint4*)&Wt[n * 128 + k0 + h + 8] = *(uint4*)&tmp[8];
    }
  } else {
    const int tid = threadIdx.x;
    for (int idx = tid; idx < 48 * 256; idx += 256) {
      int j = idx >> 8, k = idx & 255;
      lwt[idx] = (j < 40) ? f2bf(lw[k * 40 + j]) : (u16)0;
    }
  }
}

// ---------------- CSR build: binned two-pass, sentinel-padded to 8 ----------------

__global__ void zero_int_kernel(int* __restrict__ p, int n) {
  int i = blockIdx.x * blockDim.x + threadIdx.x;
  if (i < n) p[i] = 0;
}

// Pass 1: tile-local histogram+reorder in LDS, flush bucket-runs to packed buf.
__global__ __launch_bounds__(256) void partition_kernel(
    const int* __restrict__ ei, int* __restrict__ gcursor, uint32* __restrict__ packed)
{
  __shared__ int hist[NBK];
  __shared__ int s[256];
  __shared__ int scanb[NBK];
  __shared__ int gofs[NBK];
  __shared__ uint32 shuf[TILE];
  __shared__ unsigned char sbkt[TILE];
  const int tid = threadIdx.x;
  const int t0 = blockIdx.x * TILE;
  for (int i = tid; i < NBK; i += 256) hist[i] = 0;
  __syncthreads();
  int myb[16]; int myr[16]; uint32 mypk[16];
#pragma unroll
  for (int i = 0; i < 16; ++i) {
    int e = t0 + i * 256 + tid;
    myb[i] = -1;
    if (e < ET) {
      int src, dst;
      if (e < E0) { src = ei[e]; dst = ei[E0 + e]; }
      else        { src = e - E0; dst = src; }
      myb[i] = dst >> 8;
      mypk[i] = ((uint32)(dst & 255) << 16) | (uint32)src;
      myr[i] = atomicAdd(&hist[myb[i]], 1);
    }
  }
  __syncthreads();
  int v = (tid < NBK) ? hist[tid] : 0;
  int val = v;
  s[tid] = val;
  __syncthreads();
#pragma unroll
  for (int off = 1; off < 256; off <<= 1) {
    int t = (tid >= off) ? s[tid - off] : 0;
    __syncthreads();
    val += t;
    s[tid] = val;
    __syncthreads();
  }
  if (tid < NBK) {
    scanb[tid] = val - v;
    gofs[tid] = (v > 0) ? atomicAdd(&gcursor[tid], v) : 0;
  }
  __syncthreads();
#pragma unroll
  for (int i = 0; i < 16; ++i) {
    if (myb[i] >= 0) {
      int slot = scanb[myb[i]] + myr[i];
      shuf[slot] = mypk[i];
      sbkt[slot] = (unsigned char)myb[i];
    }
  }
  __syncthreads();
  const int tcount = (t0 + TILE <= ET) ? TILE : (ET - t0);
  for (int i = tid; i < tcount; i += 256) {
    int b = sbkt[i];
    packed[(size_t)b * CAP + gofs[b] + (i - scanb[b])] = shuf[i];
  }
}

// Pass 2: per bucket, padded local CSR in LDS (sentinel = NN), coalesced writes.
// Fixed region b*CAP; per-node (beg, padded_cnt) in rowinfo.
__global__ __launch_bounds__(256) void build_kernel(
    const uint32* __restrict__ packed, const int* __restrict__ gcursor,
    int2* __restrict__ rowinfo, int* __restrict__ csr_src)
{
  __shared__ int h[256];
  __shared__ int s[256];
  __shared__ int sc[256];
  __shared__ int cur[256];
  __shared__ int ptot_s;
  __shared__ u16 simg[CAP];
  const int b = blockIdx.x;
  const int tid = threadIdx.x;
  const int cnt = gcursor[b];
  const uint32* pk = packed + (size_t)b * CAP;
  h[tid] = 0;
  cur[tid] = 0;
  __syncthreads();
  for (int i = tid; i < cnt; i += 256) atomicAdd(&h[(pk[i] >> 16) & 255], 1);
  __syncthreads();
  const int pd = (h[tid] + 7) & ~7;   // pad to multiple of 8
  int val = pd;
  s[tid] = val;
  __syncthreads();
#pragma unroll
  for (int off = 1; off < 256; off <<= 1) {
    int t = (tid >= off) ? s[tid - off] : 0;
    __syncthreads();
    val += t;
    s[tid] = val;
    __syncthreads();
  }
  sc[tid] = val - pd;
  if (tid == 255) ptot_s = val;
  __syncthreads();
  const int ptot = ptot_s;
  for (int i = tid; i < ptot; i += 256) simg[i] = (u16)NN;   // sentinel fill
  __syncthreads();
  for (int i = tid; i < cnt; i += 256) {
    uint32 p = pk[i];
    int dl = (p >> 16) & 255;
    int r = atomicAdd(&cur[dl], 1);
    simg[sc[dl] + r] = (u16)(p & 0xFFFFu);
  }
  __syncthreads();
  int n = b * 256 + tid;
  if (n < NN) rowinfo[n] = make_int2(b * CAP + sc[tid], pd);
  for (int i = tid; i < ptot; i += 256) csr_src[b * CAP + i] = (int)simg[i];
}

// ---------------- MFMA GEMM (Xb @ W) + attention logits ----------------
__global__ __launch_bounds__(256) void gemm_att_kernel(
    const u16* __restrict__ Xb, const u16* __restrict__ Wt,
    const float* __restrict__ avs, const float* __restrict__ avd,
    u16* __restrict__ hfeat, float* __restrict__ es, float* __restrict__ ed,
    int nnodes)
{
  __shared__ u16 Xs[64 * 136];    // 17.0 KB, padded stride 136
  __shared__ u16 Ws[128 * 136];   // 34.0 KB (reused as bf16 out-staging)
  __shared__ float es_s[2][64];
  __shared__ float ed_s[2][64];
  const int tid = threadIdx.x;
  const int wid = tid >> 6, lane = tid & 63;
  const int quad = lane >> 4, lc = lane & 15;
  const int n0 = blockIdx.x * 64;
  if (tid < 128) { es_s[tid >> 6][tid & 63] = 0.f; ed_s[tid >> 6][tid & 63] = 0.f; }
  if (blockIdx.x == 0 && tid < 2) es[2 * NN + tid] = -1e30f;  // sentinel logits -> w=0

#pragma unroll
  for (int it = 0; it < 4; ++it) {    // Xs: 64 x 128 bf16
    int g = tid + it * 256;
    int r = g >> 4, c8 = (g & 15) * 8;
    uint4 v = make_uint4(0u, 0u, 0u, 0u);
    if (n0 + r < nnodes) v = *(const uint4*)&Xb[(size_t)(n0 + r) * 128 + c8];
    *(uint4*)&Xs[r * 136 + c8] = v;
  }
#pragma unroll
  for (int it = 0; it < 8; ++it) {    // Ws: 128 x 128 bf16 (transposed W)
    int g = tid + it * 256;
    int r = g >> 4, c8 = (g & 15) * 8;
    uint4 v = *(const uint4*)&Wt[r * 128 + c8];
    *(uint4*)&Ws[r * 136 + c8] = v;
  }
  __syncthreads();

  f32x4 acc[8];
#pragma unroll
  for (int t = 0; t < 8; ++t) acc[t] = (f32x4){0.f, 0.f, 0.f, 0.f};
  const int arow = wid * 16 + lc;
#pragma unroll 1
  for (int ks = 0; ks < 4; ++ks) {
    const int k0 = ks * 32 + quad * 8;
    bf16x8 a = *(const bf16x8*)&Xs[arow * 136 + k0];
#pragma unroll
    for (int t = 0; t < 8; ++t) {
      bf16x8 b = *(const bf16x8*)&Ws[(t * 16 + lc) * 136 + k0];
      acc[t] = __builtin_amdgcn_mfma_f32_16x16x32_bf16(a, b, acc[t], 0, 0, 0);
    }
  }

  float av_s[8], av_d[8];
#pragma unroll
  for (int t = 0; t < 8; ++t) { av_s[t] = avs[t * 16 + lc]; av_d[t] = avd[t * 16 + lc]; }
#pragma unroll
  for (int r = 0; r < 4; ++r) {
    float s0 = 0.f, s1 = 0.f, d0 = 0.f, d1 = 0.f;
#pragma unroll
    for (int t = 0; t < 4; ++t) { s0 += acc[t][r] * av_s[t]; d0 += acc[t][r] * av_d[t]; }
#pragma unroll
    for (int t = 4; t < 8; ++t) { s1 += acc[t][r] * av_s[t]; d1 += acc[t][r] * av_d[t]; }
    int row = wid * 16 + quad * 4 + r;
    atomicAdd(&es_s[0][row], s0); atomicAdd(&es_s[1][row], s1);
    atomicAdd(&ed_s[0][row], d0); atomicAdd(&ed_s[1][row], d1);
  }
  __syncthreads();
  u16* hout = Ws;
#pragma unroll
  for (int t = 0; t < 8; ++t)
#pragma unroll
    for (int r = 0; r < 4; ++r)
      hout[(wid * 16 + quad * 4 + r) * 136 + t * 16 + lc] = f2bf(acc[t][r]);
  __syncthreads();
#pragma unroll
  for (int it = 0; it < 4; ++it) {
    int g = tid + it * 256;
    int r = g >> 4, c8 = (g & 15) * 8;
    if (n0 + r < nnodes)
      *(uint4*)&hfeat[(size_t)(n0 + r) * 128 + c8] = *(const uint4*)&hout[r * 136 + c8];
  }
  if (tid < 64) {
    int n = n0 + tid;
    if (n < nnodes) {
      es[n * 2 + 0] = es_s[0][tid]; es[n * 2 + 1] = es_s[1][tid];
      ed[n * 2 + 0] = ed_s[0][tid]; ed[n * 2 + 1] = ed_s[1][tid];
    }
  }
}

// ---------------- aggregation: one wave per node, 8 edges/iter, sentinel-padded ----------------
// Quarter-wave (16 lanes) covers one edge's 256 B row as uint4; lane handles edges
// eg and eg+4 of each 8-chunk. All chunks full (sentinel src=NN has w=0) -> no bounds
// logic; 2 gathers in flight. Lane-local edge order identical to the 4-chunk version.
__global__ __launch_bounds__(256) void aggregate_kernel(
    const uint4* __restrict__ hfeat4, const float* __restrict__ es, const float* __restrict__ ed,
    const int2* __restrict__ rowinfo, const int* __restrict__ csr_src,
    const float* __restrict__ bias, u16* __restrict__ out, int nnodes)
{
  int n = (blockIdx.x * blockDim.x + threadIdx.x) >> 6;
  int lane = threadIdx.x & 63;
  if (n >= nnodes) return;
  const int eg = lane >> 4;
  const int fl = lane & 15;
  const int hd = (fl >= 8) ? 1 : 0;
  const int2 ri = rowinfo[n];
  const int nch = ri.y >> 3;
  const int j0 = ri.x + eg;
  const float edn = ed[n * 2 + hd];

  float acc[8];
#pragma unroll
  for (int t = 0; t < 8; ++t) acc[t] = 0.f;
  float den = 0.f;

  int i0A = csr_src[j0], i1A = csr_src[j0 + 4];
  float e0 = es[i0A * 2 + hd] + edn; e0 = fmaxf(e0, 0.2f * e0);
  float e1 = es[i1A * 2 + hd] + edn; e1 = fmaxf(e1, 0.2f * e1);
  float w0A = __expf(e0), w1A = __expf(e1);
  for (int c = 0;;) {
    uint4 h0 = hfeat4[(size_t)i0A * 16 + fl];
    uint4 h1 = hfeat4[(size_t)i1A * 16 + fl];
    bool more = (c + 1 < nch);
    int i0B, i1B; float w0B, w1B;
    if (more) {
      int jb = j0 + (c + 1) * 8;
      i0B = csr_src[jb]; i1B = csr_src[jb + 4];
      float f0 = es[i0B * 2 + hd] + edn; f0 = fmaxf(f0, 0.2f * f0);
      float f1 = es[i1B * 2 + hd] + edn; f1 = fmaxf(f1, 0.2f * f1);
      w0B = __expf(f0); w1B = __expf(f1);
    }
    acc[0] = fmaf(w0A, bflo(h0.x), acc[0]);
    acc[1] = fmaf(w0A, bfhi(h0.x), acc[1]);
    acc[2] = fmaf(w0A, bflo(h0.y), acc[2]);
    acc[3] = fmaf(w0A, bfhi(h0.y), acc[3]);
    acc[4] = fmaf(w0A, bflo(h0.z), acc[4]);
    acc[5] = fmaf(w0A, bfhi(h0.z), acc[5]);
    acc[6] = fmaf(w0A, bflo(h0.w), acc[6]);
    acc[7] = fmaf(w0A, bfhi(h0.w), acc[7]);
    acc[0] = fmaf(w1A, bflo(h1.x), acc[0]);
    acc[1] = fmaf(w1A, bfhi(h1.x), acc[1]);
    acc[2] = fmaf(w1A, bflo(h1.y), acc[2]);
    acc[3] = fmaf(w1A, bfhi(h1.y), acc[3]);
    acc[4] = fmaf(w1A, bflo(h1.z), acc[4]);
    acc[5] = fmaf(w1A, bfhi(h1.z), acc[5]);
    acc[6] = fmaf(w1A, bflo(h1.w), acc[6]);
    acc[7] = fmaf(w1A, bfhi(h1.w), acc[7]);
    den += w0A + w1A;
    if (!more) break;
    i0A = i0B; i1A = i1B; w0A = w0B; w1A = w1B;
    ++c;
  }

#pragma unroll
  for (int t = 0; t < 8; ++t) {
    acc[t] += __shfl_xor(acc[t], 16);
    acc[t] += __shfl_xor(acc[t], 32);
  }
  den += __shfl_xor(den, 16);
  den += __shfl_xor(den, 32);

  if (eg == 0) {
    float inv = 1.f / den;
    float4 b0 = *(const float4*)&bias[fl * 8];
    float4 b1 = *(const float4*)&bias[fl * 8 + 4];
    float bv[8] = {b0.x, b0.y, b0.z, b0.w, b1.x, b1.y, b1.z, b1.w};
    u16 pk[8];
#pragma unroll
    for (int t = 0; t < 8; ++t) {
      float v = acc[t] * inv + bv[t];
      v = (v > 0.f) ? v : (__expf(v) - 1.f);  // ELU
      pk[t] = f2bf(v);
    }
    uint4 o;
    o.x = (uint32)pk[0] | ((uint32)pk[1] << 16);
    o.y = (uint32)pk[2] | ((uint32)pk[3] << 16);
    o.z = (uint32)pk[4] | ((uint32)pk[5] << 16);
    o.w = (uint32)pk[6] | ((uint32)pk[7] << 16);
    ((uint4*)out)[(size_t)n * 16 + fl] = o;
  }
}

// ---------------- final: MFMA [64x256] @ [256x48] + log_softmax on fragments ----------------
#define FS 264
__global__ __launch_bounds__(256) void final_kernel(
    const u16* __restrict__ h1b, const u16* __restrict__ h2b,
    const u16* __restrict__ lwt, const float* __restrict__ lb,
    float* __restrict__ out, int nnodes)
{
  __shared__ u16 Hs[64 * FS];
  __shared__ u16 Ls[48 * FS];
  const int tid = threadIdx.x;
  const int wid = tid >> 6, lane = tid & 63;
  const int quad = lane >> 4, lc = lane & 15;
  const int n0 = blockIdx.x * 64;

#pragma unroll
  for (int it = 0; it < 8; ++it) {
    int g = tid + it * 256;
    int r = g >> 5, c8 = (g & 31) * 8;
    uint4 v = make_uint4(0u, 0u, 0u, 0u);
    if (n0 + r < nnodes) {
      const u16* src = (c8 < 128) ? &h1b[(size_t)(n0 + r) * 128 + c8]
                                  : &h2b[(size_t)(n0 + r) * 128 + (c8 - 128)];
      v = *(const uint4*)src;
    }
    *(uint4*)&Hs[r * FS + c8] = v;
  }
#pragma unroll
  for (int it = 0; it < 6; ++it) {
    int g = tid + it * 256;
    int r = g >> 5, c8 = (g & 31) * 8;
    *(uint4*)&Ls[r * FS + c8] = *(const uint4*)&lwt[r * 256 + c8];
  }
  __syncthreads();

  f32x4 acc[3];
#pragma unroll
  for (int t = 0; t < 3; ++t) acc[t] = (f32x4){0.f, 0.f, 0.f, 0.f};
  const int arow = wid * 16 + lc;
#pragma unroll
  for (int ks = 0; ks < 8; ++ks) {
    const int k0 = ks * 32 + quad * 8;
    bf16x8 a = *(const bf16x8*)&Hs[arow * FS + k0];
#pragma unroll
    for (int t = 0; t < 3; ++t) {
      bf16x8 b = *(const bf16x8*)&Ls[(t * 16 + lc) * FS + k0];
      acc[t] = __builtin_amdgcn_mfma_f32_16x16x32_bf16(a, b, acc[t], 0, 0, 0);
    }
  }

  float bv[3];
  bool valid[3];
#pragma unroll
  for (int t = 0; t < 3; ++t) {
    int col = t * 16 + lc;
    valid[t] = (col < 40);
    bv[t] = valid[t] ? lb[col] : 0.f;
  }
#pragma unroll
  for (int r = 0; r < 4; ++r) {
    int row = wid * 16 + quad * 4 + r;
    int n = n0 + row;
    float v[3];
    float mx = -INFINITY;
#pragma unroll
    for (int t = 0; t < 3; ++t) {
      v[t] = acc[t][r] + bv[t];
      if (valid[t]) mx = fmaxf(mx, v[t]);
    }
    mx = fmaxf(mx, __shfl_xor(mx, 1));
    mx = fmaxf(mx, __shfl_xor(mx, 2));
    mx = fmaxf(mx, __shfl_xor(mx, 4));
    mx = fmaxf(mx, __shfl_xor(mx, 8));
    float s = 0.f;
#pragma unroll
    for (int t = 0; t < 3; ++t) if (valid[t]) s += __expf(v[t] - mx);
    s += __shfl_xor(s, 1);
    s += __shfl_xor(s, 2);
    s += __shfl_xor(s, 4);
    s += __shfl_xor(s, 8);
    float lg = mx + __logf(s);
    if (n < nnodes) {
#pragma unroll
      for (int t = 0; t < 3; ++t)
        if (valid[t]) out[(size_t)n * 40 + t * 16 + lc] = v[t] - lg;
    }
  }
}

// ---------------- launch ----------------

extern "C" void kernel_launch(void* const* d_in, const int* in_sizes, int n_in,
                              void* d_out, int out_size, void* d_ws, size_t ws_size,
                              hipStream_t stream) {
  const float* x   = (const float*)d_in[0];
  const int*   ei  = (const int*)d_in[1];
  const float* W0  = (const float*)d_in[2];
  const float* as0 = (const float*)d_in[3];
  const float* ad0 = (const float*)d_in[4];
  const float* b0  = (const float*)d_in[5];
  const float* W1  = (const float*)d_in[6];
  const float* as1 = (const float*)d_in[7];
  const float* ad1 = (const float*)d_in[8];
  const float* b1  = (const float*)d_in[9];
  const float* lw  = (const float*)d_in[10];
  const float* lb  = (const float*)d_in[11];
  float* out = (float*)d_out;

  char* p = (char*)d_ws;
  auto carve = [&](size_t bytes) { char* r = p; p += (bytes + 255) & ~(size_t)255; return r; };
  u16* xb     = (u16*)carve((size_t)NN * 128 * 2);
  u16* w0t    = (u16*)carve(128 * 128 * 2);
  u16* w1t    = (u16*)carve(128 * 128 * 2);
  u16* lwt    = (u16*)carve(48 * 256 * 2);
  u16* hfeat  = (u16*)carve((size_t)(NN + 1) * 128 * 2);  // +1 sentinel row
  u16* h1b    = (u16*)carve((size_t)NN * 128 * 2);
  u16* h2b    = (u16*)carve((size_t)NN * 128 * 2);
  float* es   = (float*)carve((size_t)(NN + 1) * 2 * 4);  // +sentinel logits
  float* ed   = (float*)carve((size_t)NN * 2 * 4);
  int2* rowinfo = (int2*)carve((size_t)NN * 8);
  int* csr    = (int*)carve((size_t)NBK * CAP * 4);
  uint32* packed = (uint32*)carve((size_t)NBK * CAP * 4);
  int* gcursor = (int*)carve(NBK * 4);

  // prep (bf16 conversions + transposes)
  prep_kernel<<<NBX + 3, 256, 0, stream>>>(x, W0, W1, lw, xb, w0t, w1t, lwt);

  // CSR build: binned two-pass, sentinel-padded
  zero_int_kernel<<<1, 256, 0, stream>>>(gcursor, NBK);
  partition_kernel<<<NTILES, 256, 0, stream>>>(ei, gcursor, packed);
  build_kernel<<<NBK, 256, 0, stream>>>(packed, gcursor, rowinfo, csr);

  // layer 1
  gemm_att_kernel<<<(NN + 63) / 64, 256, 0, stream>>>(xb, w0t, as0, ad0, hfeat, es, ed, NN);
  aggregate_kernel<<<(NN * 64 + 255) / 256, 256, 0, stream>>>((const uint4*)hfeat, es, ed, rowinfo, csr, b0, h1b, NN);
  // layer 2
  gemm_att_kernel<<<(NN + 63) / 64, 256, 0, stream>>>(h1b, w1t, as1, ad1, hfeat, es, ed, NN);
  aggregate_kernel<<<(NN * 64 + 255) / 256, 256, 0, stream>>>((const uint4*)hfeat, es, ed, rowinfo, csr, b1, h2b, NN);
  // head
  final_kernel<<<(NN + 63) / 64, 256, 0, stream>>>(h1b, h2b, lwt, lb, out, NN);
}

// Round 14
// 249.732 us; speedup vs baseline: 14.4631x; 1.1207x over previous
//
#include <hip/hip_runtime.h>
#include <math.h>

#define NN 50000
#define E0 800000
#define ET 850000
#define NBX 200  // prep: x-conversion blocks (+2 W transposes, +1 lw transpose)
#define NBK 196  // CSR buckets = ceil(NN/256), 256 nodes each
#define TILE 4096
#define NTILES 208  // ceil(ET/TILE)
#define CAP 8192    // per-bucket region (packed & padded csr)

typedef unsigned int uint32;
typedef unsigned short u16;
typedef __attribute__((ext_vector_type(8))) short bf16x8;  // 8 bf16 = 4 VGPRs
typedef __attribute__((ext_vector_type(4))) float f32x4;

__device__ __forceinline__ u16 f2bf(float f) {
  uint32 u = __float_as_uint(f);
  return (u16)((u + 0x7FFFu + ((u >> 16) & 1u)) >> 16);  // RNE
}
__device__ __forceinline__ float bflo(uint32 u) { return __uint_as_float(u << 16); }
__device__ __forceinline__ float bfhi(uint32 u) { return __uint_as_float(u & 0xFFFF0000u); }

// ---- prep: x -> bf16; W0,W1 -> bf16 transposed [n][k]; lw -> bf16 T [48][256] ----
__global__ __launch_bounds__(256) void prep_kernel(
    const float* __restrict__ x, const float* __restrict__ W0, const float* __restrict__ W1,
    const float* __restrict__ lw,
    u16* __restrict__ xb, u16* __restrict__ w0t, u16* __restrict__ w1t, u16* __restrict__ lwt)
{
  int b = blockIdx.x;
  if (b < NBX) {
    const float4* x4 = (const float4*)x;
    ushort4* xb4 = (ushort4*)xb;
    const int total = NN * 128 / 4;
    for (int i = b * 256 + threadIdx.x; i < total; i += NBX * 256) {
      float4 v = x4[i];
      ushort4 u;
      u.x = f2bf(v.x); u.y = f2bf(v.y); u.z = f2bf(v.z); u.w = f2bf(v.w);
      xb4[i] = u;
    }
  } else if (b < NBX + 2) {
    const float* W = (b == NBX) ? W0 : W1;
    u16* Wt = (b == NBX) ? w0t : w1t;
    __shared__ float tile[32][129];
    const int tid = threadIdx.x;
    for (int k0 = 0; k0 < 128; k0 += 32) {
      __syncthreads();
#pragma unroll
      for (int it = 0; it < 4; ++it) {
        int q = tid + it * 256;
        int kk = q >> 5, n4 = (q & 31) * 4;
        float4 v = *(const float4*)&W[(k0 + kk) * 128 + n4];
        tile[kk][n4 + 0] = v.x; tile[kk][n4 + 1] = v.y;
        tile[kk][n4 + 2] = v.z; tile[kk][n4 + 3] = v.w;
      }
      __syncthreads();
      int n = tid >> 1, h = (tid & 1) * 16;
      __align__(16) u16 tmp[16];
#pragma unroll
      for (int j = 0; j < 16; ++j) tmp[j] = f2bf(tile[h + j][n]);
      *(uint4*)&Wt[n * 128 + k0 + h] = *(uint4*)&tmp[0];
      *(uint4*)&Wt[n * 128 + k0 + h + 8] = *(uint4*)&tmp[8];
    }
  } else {
    const int tid = threadIdx.x;
    for (int idx = tid; idx < 48 * 256; idx += 256) {
      int j = idx >> 8, k = idx & 255;
      lwt[idx] = (j < 40) ? f2bf(lw[k * 40 + j]) : (u16)0;
    }
  }
}

// ---------------- CSR build: binned two-pass, sentinel-padded to 8 ----------------

__global__ void zero_int_kernel(int* __restrict__ p, int n) {
  int i = blockIdx.x * blockDim.x + threadIdx.x;
  if (i < n) p[i] = 0;
}

// Pass 1: tile-local histogram+reorder in LDS, flush bucket-runs to packed buf.
__global__ __launch_bounds__(256) void partition_kernel(
    const int* __restrict__ ei, int* __restrict__ gcursor, uint32* __restrict__ packed)
{
  __shared__ int hist[NBK];
  __shared__ int s[256];
  __shared__ int scanb[NBK];
  __shared__ int gofs[NBK];
  __shared__ uint32 shuf[TILE];
  __shared__ unsigned char sbkt[TILE];
  const int tid = threadIdx.x;
  const int t0 = blockIdx.x * TILE;
  for (int i = tid; i < NBK; i += 256) hist[i] = 0;
  __syncthreads();
  int myb[16]; int myr[16]; uint32 mypk[16];
#pragma unroll
  for (int i = 0; i < 16; ++i) {
    int e = t0 + i * 256 + tid;
    myb[i] = -1;
    if (e < ET) {
      int src, dst;
      if (e < E0) { src = ei[e]; dst = ei[E0 + e]; }
      else        { src = e - E0; dst = src; }
      myb[i] = dst >> 8;
      mypk[i] = ((uint32)(dst & 255) << 16) | (uint32)src;
      myr[i] = atomicAdd(&hist[myb[i]], 1);
    }
  }
  __syncthreads();
  int v = (tid < NBK) ? hist[tid] : 0;
  int val = v;
  s[tid] = val;
  __syncthreads();
#pragma unroll
  for (int off = 1; off < 256; off <<= 1) {
    int t = (tid >= off) ? s[tid - off] : 0;
    __syncthreads();
    val += t;
    s[tid] = val;
    __syncthreads();
  }
  if (tid < NBK) {
    scanb[tid] = val - v;
    gofs[tid] = (v > 0) ? atomicAdd(&gcursor[tid], v) : 0;
  }
  __syncthreads();
#pragma unroll
  for (int i = 0; i < 16; ++i) {
    if (myb[i] >= 0) {
      int slot = scanb[myb[i]] + myr[i];
      shuf[slot] = mypk[i];
      sbkt[slot] = (unsigned char)myb[i];
    }
  }
  __syncthreads();
  const int tcount = (t0 + TILE <= ET) ? TILE : (ET - t0);
  for (int i = tid; i < tcount; i += 256) {
    int b = sbkt[i];
    packed[(size_t)b * CAP + gofs[b] + (i - scanb[b])] = shuf[i];
  }
}

// Pass 2: per bucket, padded local CSR in LDS (sentinel = NN), coalesced writes.
__global__ __launch_bounds__(256) void build_kernel(
    const uint32* __restrict__ packed, const int* __restrict__ gcursor,
    int2* __restrict__ rowinfo, int* __restrict__ csr_src)
{
  __shared__ int h[256];
  __shared__ int s[256];
  __shared__ int sc[256];
  __shared__ int cur[256];
  __shared__ int ptot_s;
  __shared__ u16 simg[CAP];
  const int b = blockIdx.x;
  const int tid = threadIdx.x;
  const int cnt = gcursor[b];
  const uint32* pk = packed + (size_t)b * CAP;
  h[tid] = 0;
  cur[tid] = 0;
  __syncthreads();
  for (int i = tid; i < cnt; i += 256) atomicAdd(&h[(pk[i] >> 16) & 255], 1);
  __syncthreads();
  const int pd = (h[tid] + 7) & ~7;   // pad to multiple of 8
  int val = pd;
  s[tid] = val;
  __syncthreads();
#pragma unroll
  for (int off = 1; off < 256; off <<= 1) {
    int t = (tid >= off) ? s[tid - off] : 0;
    __syncthreads();
    val += t;
    s[tid] = val;
    __syncthreads();
  }
  sc[tid] = val - pd;
  if (tid == 255) ptot_s = val;
  __syncthreads();
  const int ptot = ptot_s;
  for (int i = tid; i < ptot; i += 256) simg[i] = (u16)NN;   // sentinel fill
  __syncthreads();
  for (int i = tid; i < cnt; i += 256) {
    uint32 p = pk[i];
    int dl = (p >> 16) & 255;
    int r = atomicAdd(&cur[dl], 1);
    simg[sc[dl] + r] = (u16)(p & 0xFFFFu);
  }
  __syncthreads();
  int n = b * 256 + tid;
  if (n < NN) rowinfo[n] = make_int2(b * CAP + sc[tid], pd);
  for (int i = tid; i < ptot; i += 256) csr_src[b * CAP + i] = (int)simg[i];
}

// ---------------- MFMA GEMM (Xb @ W) + attention logits ----------------
// v2: no Ws LDS (B-frags straight from L1-resident Wt); shuffle-reduced partials.
__global__ __launch_bounds__(256) void gemm_att_kernel(
    const u16* __restrict__ Xb, const u16* __restrict__ Wt,
    const float* __restrict__ avs, const float* __restrict__ avd,
    u16* __restrict__ hfeat, float* __restrict__ es, float* __restrict__ ed,
    int nnodes)
{
  __shared__ u16 Xs[64 * 136];    // 17.4 KB (reused as hout after the compute barrier)
  __shared__ float es_s[2][64];
  __shared__ float ed_s[2][64];
  const int tid = threadIdx.x;
  const int wid = tid >> 6, lane = tid & 63;
  const int quad = lane >> 4, lc = lane & 15;
  const int n0 = blockIdx.x * 64;
  if (blockIdx.x == 0 && tid < 2) es[2 * NN + tid] = -1e30f;  // sentinel logits -> w=0

#pragma unroll
  for (int it = 0; it < 4; ++it) {    // Xs: 64 x 128 bf16
    int g = tid + it * 256;
    int r = g >> 4, c8 = (g & 15) * 8;
    uint4 v = make_uint4(0u, 0u, 0u, 0u);
    if (n0 + r < nnodes) v = *(const uint4*)&Xb[(size_t)(n0 + r) * 128 + c8];
    *(uint4*)&Xs[r * 136 + c8] = v;
  }
  __syncthreads();

  f32x4 acc[8];
#pragma unroll
  for (int t = 0; t < 8; ++t) acc[t] = (f32x4){0.f, 0.f, 0.f, 0.f};
  const int arow = wid * 16 + lc;
#pragma unroll
  for (int ks = 0; ks < 4; ++ks) {
    const int k0 = ks * 32 + quad * 8;
    bf16x8 a = *(const bf16x8*)&Xs[arow * 136 + k0];
#pragma unroll
    for (int t = 0; t < 8; ++t) {
      bf16x8 b = *(const bf16x8*)&Wt[(t * 16 + lc) * 128 + k0];  // L1-resident
      acc[t] = __builtin_amdgcn_mfma_f32_16x16x32_bf16(a, b, acc[t], 0, 0, 0);
    }
  }

  // attention partials: quad-local shuffle reduction (single writer, no atomics)
  float av_s[8], av_d[8];
#pragma unroll
  for (int t = 0; t < 8; ++t) { av_s[t] = avs[t * 16 + lc]; av_d[t] = avd[t * 16 + lc]; }
#pragma unroll
  for (int r = 0; r < 4; ++r) {
    float s0 = 0.f, s1 = 0.f, d0 = 0.f, d1 = 0.f;
#pragma unroll
    for (int t = 0; t < 4; ++t) { s0 += acc[t][r] * av_s[t]; d0 += acc[t][r] * av_d[t]; }
#pragma unroll
    for (int t = 4; t < 8; ++t) { s1 += acc[t][r] * av_s[t]; d1 += acc[t][r] * av_d[t]; }
#pragma unroll
    for (int m = 1; m < 16; m <<= 1) {
      s0 += __shfl_xor(s0, m); s1 += __shfl_xor(s1, m);
      d0 += __shfl_xor(d0, m); d1 += __shfl_xor(d1, m);
    }
    if (lc == 0) {
      int row = wid * 16 + quad * 4 + r;
      es_s[0][row] = s0; es_s[1][row] = s1;
      ed_s[0][row] = d0; ed_s[1][row] = d1;
    }
  }
  __syncthreads();              // Xs reads done -> reuse as bf16 out-staging
  u16* hout = Xs;               // 64 rows x stride 136
#pragma unroll
  for (int t = 0; t < 8; ++t)
#pragma unroll
    for (int r = 0; r < 4; ++r)
      hout[(wid * 16 + quad * 4 + r) * 136 + t * 16 + lc] = f2bf(acc[t][r]);
  __syncthreads();
#pragma unroll
  for (int it = 0; it < 4; ++it) {   // coalesced bf16 writeback
    int g = tid + it * 256;
    int r = g >> 4, c8 = (g & 15) * 8;
    if (n0 + r < nnodes)
      *(uint4*)&hfeat[(size_t)(n0 + r) * 128 + c8] = *(const uint4*)&hout[r * 136 + c8];
  }
  if (tid < 64) {
    int n = n0 + tid;
    if (n < nnodes) {
      es[n * 2 + 0] = es_s[0][tid]; es[n * 2 + 1] = es_s[1][tid];
      ed[n * 2 + 0] = ed_s[0][tid]; ed[n * 2 + 1] = ed_s[1][tid];
    }
  }
}

// ---------------- aggregation: one wave per node, 8 edges/iter, sentinel-padded ----------------
__global__ __launch_bounds__(256) void aggregate_kernel(
    const uint4* __restrict__ hfeat4, const float* __restrict__ es, const float* __restrict__ ed,
    const int2* __restrict__ rowinfo, const int* __restrict__ csr_src,
    const float* __restrict__ bias, u16* __restrict__ out, int nnodes)
{
  int n = (blockIdx.x * blockDim.x + threadIdx.x) >> 6;
  int lane = threadIdx.x & 63;
  if (n >= nnodes) return;
  const int eg = lane >> 4;
  const int fl = lane & 15;
  const int hd = (fl >= 8) ? 1 : 0;
  const int2 ri = rowinfo[n];
  const int nch = ri.y >> 3;
  const int j0 = ri.x + eg;
  const float edn = ed[n * 2 + hd];

  float acc[8];
#pragma unroll
  for (int t = 0; t < 8; ++t) acc[t] = 0.f;
  float den = 0.f;

  int i0A = csr_src[j0], i1A = csr_src[j0 + 4];
  float e0 = es[i0A * 2 + hd] + edn; e0 = fmaxf(e0, 0.2f * e0);
  float e1 = es[i1A * 2 + hd] + edn; e1 = fmaxf(e1, 0.2f * e1);
  float w0A = __expf(e0), w1A = __expf(e1);
  for (int c = 0;;) {
    uint4 h0 = hfeat4[(size_t)i0A * 16 + fl];
    uint4 h1 = hfeat4[(size_t)i1A * 16 + fl];
    bool more = (c + 1 < nch);
    int i0B, i1B; float w0B, w1B;
    if (more) {
      int jb = j0 + (c + 1) * 8;
      i0B = csr_src[jb]; i1B = csr_src[jb + 4];
      float f0 = es[i0B * 2 + hd] + edn; f0 = fmaxf(f0, 0.2f * f0);
      float f1 = es[i1B * 2 + hd] + edn; f1 = fmaxf(f1, 0.2f * f1);
      w0B = __expf(f0); w1B = __expf(f1);
    }
    acc[0] = fmaf(w0A, bflo(h0.x), acc[0]);
    acc[1] = fmaf(w0A, bfhi(h0.x), acc[1]);
    acc[2] = fmaf(w0A, bflo(h0.y), acc[2]);
    acc[3] = fmaf(w0A, bfhi(h0.y), acc[3]);
    acc[4] = fmaf(w0A, bflo(h0.z), acc[4]);
    acc[5] = fmaf(w0A, bfhi(h0.z), acc[5]);
    acc[6] = fmaf(w0A, bflo(h0.w), acc[6]);
    acc[7] = fmaf(w0A, bfhi(h0.w), acc[7]);
    acc[0] = fmaf(w1A, bflo(h1.x), acc[0]);
    acc[1] = fmaf(w1A, bfhi(h1.x), acc[1]);
    acc[2] = fmaf(w1A, bflo(h1.y), acc[2]);
    acc[3] = fmaf(w1A, bfhi(h1.y), acc[3]);
    acc[4] = fmaf(w1A, bflo(h1.z), acc[4]);
    acc[5] = fmaf(w1A, bfhi(h1.z), acc[5]);
    acc[6] = fmaf(w1A, bflo(h1.w), acc[6]);
    acc[7] = fmaf(w1A, bfhi(h1.w), acc[7]);
    den += w0A + w1A;
    if (!more) break;
    i0A = i0B; i1A = i1B; w0A = w0B; w1A = w1B;
    ++c;
  }

#pragma unroll
  for (int t = 0; t < 8; ++t) {
    acc[t] += __shfl_xor(acc[t], 16);
    acc[t] += __shfl_xor(acc[t], 32);
  }
  den += __shfl_xor(den, 16);
  den += __shfl_xor(den, 32);

  if (eg == 0) {
    float inv = 1.f / den;
    float4 b0 = *(const float4*)&bias[fl * 8];
    float4 b1 = *(const float4*)&bias[fl * 8 + 4];
    float bv[8] = {b0.x, b0.y, b0.z, b0.w, b1.x, b1.y, b1.z, b1.w};
    u16 pk[8];
#pragma unroll
    for (int t = 0; t < 8; ++t) {
      float v = acc[t] * inv + bv[t];
      v = (v > 0.f) ? v : (__expf(v) - 1.f);  // ELU
      pk[t] = f2bf(v);
    }
    uint4 o;
    o.x = (uint32)pk[0] | ((uint32)pk[1] << 16);
    o.y = (uint32)pk[2] | ((uint32)pk[3] << 16);
    o.z = (uint32)pk[4] | ((uint32)pk[5] << 16);
    o.w = (uint32)pk[6] | ((uint32)pk[7] << 16);
    ((uint4*)out)[(size_t)n * 16 + fl] = o;
  }
}

// ---------------- final: MFMA [64x256] @ [256x48] + log_softmax on fragments ----------------
#define FS 264
__global__ __launch_bounds__(256) void final_kernel(
    const u16* __restrict__ h1b, const u16* __restrict__ h2b,
    const u16* __restrict__ lwt, const float* __restrict__ lb,
    float* __restrict__ out, int nnodes)
{
  __shared__ u16 Hs[64 * FS];
  __shared__ u16 Ls[48 * FS];
  const int tid = threadIdx.x;
  const int wid = tid >> 6, lane = tid & 63;
  const int quad = lane >> 4, lc = lane & 15;
  const int n0 = blockIdx.x * 64;

#pragma unroll
  for (int it = 0; it < 8; ++it) {
    int g = tid + it * 256;
    int r = g >> 5, c8 = (g & 31) * 8;
    uint4 v = make_uint4(0u, 0u, 0u, 0u);
    if (n0 + r < nnodes) {
      const u16* src = (c8 < 128) ? &h1b[(size_t)(n0 + r) * 128 + c8]
                                  : &h2b[(size_t)(n0 + r) * 128 + (c8 - 128)];
      v = *(const uint4*)src;
    }
    *(uint4*)&Hs[r * FS + c8] = v;
  }
#pragma unroll
  for (int it = 0; it < 6; ++it) {
    int g = tid + it * 256;
    int r = g >> 5, c8 = (g & 31) * 8;
    *(uint4*)&Ls[r * FS + c8] = *(const uint4*)&lwt[r * 256 + c8];
  }
  __syncthreads();

  f32x4 acc[3];
#pragma unroll
  for (int t = 0; t < 3; ++t) acc[t] = (f32x4){0.f, 0.f, 0.f, 0.f};
  const int arow = wid * 16 + lc;
#pragma unroll
  for (int ks = 0; ks < 8; ++ks) {
    const int k0 = ks * 32 + quad * 8;
    bf16x8 a = *(const bf16x8*)&Hs[arow * FS + k0];
#pragma unroll
    for (int t = 0; t < 3; ++t) {
      bf16x8 b = *(const bf16x8*)&Ls[(t * 16 + lc) * FS + k0];
      acc[t] = __builtin_amdgcn_mfma_f32_16x16x32_bf16(a, b, acc[t], 0, 0, 0);
    }
  }

  float bv[3];
  bool valid[3];
#pragma unroll
  for (int t = 0; t < 3; ++t) {
    int col = t * 16 + lc;
    valid[t] = (col < 40);
    bv[t] = valid[t] ? lb[col] : 0.f;
  }
#pragma unroll
  for (int r = 0; r < 4; ++r) {
    int row = wid * 16 + quad * 4 + r;
    int n = n0 + row;
    float v[3];
    float mx = -INFINITY;
#pragma unroll
    for (int t = 0; t < 3; ++t) {
      v[t] = acc[t][r] + bv[t];
      if (valid[t]) mx = fmaxf(mx, v[t]);
    }
    mx = fmaxf(mx, __shfl_xor(mx, 1));
    mx = fmaxf(mx, __shfl_xor(mx, 2));
    mx = fmaxf(mx, __shfl_xor(mx, 4));
    mx = fmaxf(mx, __shfl_xor(mx, 8));
    float s = 0.f;
#pragma unroll
    for (int t = 0; t < 3; ++t) if (valid[t]) s += __expf(v[t] - mx);
    s += __shfl_xor(s, 1);
    s += __shfl_xor(s, 2);
    s += __shfl_xor(s, 4);
    s += __shfl_xor(s, 8);
    float lg = mx + __logf(s);
    if (n < nnodes) {
#pragma unroll
      for (int t = 0; t < 3; ++t)
        if (valid[t]) out[(size_t)n * 40 + t * 16 + lc] = v[t] - lg;
    }
  }
}

// ---------------- launch ----------------

extern "C" void kernel_launch(void* const* d_in, const int* in_sizes, int n_in,
                              void* d_out, int out_size, void* d_ws, size_t ws_size,
                              hipStream_t stream) {
  const float* x   = (const float*)d_in[0];
  const int*   ei  = (const int*)d_in[1];
  const float* W0  = (const float*)d_in[2];
  const float* as0 = (const float*)d_in[3];
  const float* ad0 = (const float*)d_in[4];
  const float* b0  = (const float*)d_in[5];
  const float* W1  = (const float*)d_in[6];
  const float* as1 = (const float*)d_in[7];
  const float* ad1 = (const float*)d_in[8];
  const float* b1  = (const float*)d_in[9];
  const float* lw  = (const float*)d_in[10];
  const float* lb  = (const float*)d_in[11];
  float* out = (float*)d_out;

  char* p = (char*)d_ws;
  auto carve = [&](size_t bytes) { char* r = p; p += (bytes + 255) & ~(size_t)255; return r; };
  u16* xb     = (u16*)carve((size_t)NN * 128 * 2);
  u16* w0t    = (u16*)carve(128 * 128 * 2);
  u16* w1t    = (u16*)carve(128 * 128 * 2);
  u16* lwt    = (u16*)carve(48 * 256 * 2);
  u16* hfeat  = (u16*)carve((size_t)(NN + 1) * 128 * 2);  // +1 sentinel row
  u16* h1b    = (u16*)carve((size_t)NN * 128 * 2);
  u16* h2b    = (u16*)carve((size_t)NN * 128 * 2);
  float* es   = (float*)carve((size_t)(NN + 1) * 2 * 4);  // +sentinel logits
  float* ed   = (float*)carve((size_t)NN * 2 * 4);
  int2* rowinfo = (int2*)carve((size_t)NN * 8);
  int* csr    = (int*)carve((size_t)NBK * CAP * 4);
  uint32* packed = (uint32*)carve((size_t)NBK * CAP * 4);
  int* gcursor = (int*)carve(NBK * 4);

  // prep (bf16 conversions + transposes)
  prep_kernel<<<NBX + 3, 256, 0, stream>>>(x, W0, W1, lw, xb, w0t, w1t, lwt);

  // CSR build: binned two-pass, sentinel-padded
  zero_int_kernel<<<1, 256, 0, stream>>>(gcursor, NBK);
  partition_kernel<<<NTILES, 256, 0, stream>>>(ei, gcursor, packed);
  build_kernel<<<NBK, 256, 0, stream>>>(packed, gcursor, rowinfo, csr);

  // layer 1
  gemm_att_kernel<<<(NN + 63) / 64, 256, 0, stream>>>(xb, w0t, as0, ad0, hfeat, es, ed, NN);
  aggregate_kernel<<<(NN * 64 + 255) / 256, 256, 0, stream>>>((const uint4*)hfeat, es, ed, rowinfo, csr, b0, h1b, NN);
  // layer 2
  gemm_att_kernel<<<(NN + 63) / 64, 256, 0, stream>>>(h1b, w1t, as1, ad1, hfeat, es, ed, NN);
  aggregate_kernel<<<(NN * 64 + 255) / 256, 256, 0, stream>>>((const uint4*)hfeat, es, ed, rowinfo, csr, b1, h2b, NN);
  // head
  final_kernel<<<(NN + 63) / 64, 256, 0, stream>>>(h1b, h2b, lwt, lb, out, NN);
}